// Round 8
// baseline (804.666 us; speedup 1.0000x reference)
//
#include <hip/hip_runtime.h>

// Problem constants (match reference)
constexpr int N_OP    = 100000;
constexpr int N_M     = 2000;
constexpr int IN_DIM  = 64;
constexpr int OUT_DIM = 128;
constexpr int E_SEQ_N  = 100000;
constexpr int E_OP2M_N = 2000000;

// S layout: scan over [degOp(100000) | degSeq(100000) | trailing 0]
constexpr int OFF_SEQ2 = 100000;
constexpr int SCAN_N2  = 200001;

// Destination-range partitioning for the fill stage
constexpr int NGRP       = 8;
constexpr int OP_PER_GRP = N_OP / NGRP;   // 12500
constexpr int M_PER_GRP  = N_M / NGRP;    // 250

__device__ __forceinline__ float bf2f(unsigned short h) {
  return __uint_as_float((unsigned)h << 16);
}

// ---------------- Projection: Y[nrows,128] = X[nrows,64] @ W[64,128] + b ----------------
// Also emits a bf16 (RNE) copy Yh for the bandwidth-bound gathers.
__global__ __launch_bounds__(256) void proj_kernel(
    const float* __restrict__ X, const float* __restrict__ W,
    const float* __restrict__ b, float* __restrict__ Y,
    unsigned short* __restrict__ Yh, int nrows) {
  __shared__ float Ws[IN_DIM * OUT_DIM];   // 32 KB
  __shared__ float bs[OUT_DIM];
  __shared__ float Xs[16 * IN_DIM];        // 4 KB
  const int t = threadIdx.x;
  for (int i = t; i < IN_DIM * OUT_DIM; i += 256) Ws[i] = W[i];
  if (t < OUT_DIM) bs[t] = b[t];
  const int row0 = blockIdx.x * 16;
  const int nr = min(16, nrows - row0);
  for (int i = t; i < nr * IN_DIM; i += 256) Xs[i] = X[(size_t)row0 * IN_DIM + i];
  __syncthreads();
  const int c = t & 127;
  #pragma unroll
  for (int k = 0; k < 8; ++k) {
    const int o = t + k * 256;
    const int r = o >> 7;
    if (r >= nr) break;
    float acc = bs[c];
    #pragma unroll
    for (int j = 0; j < IN_DIM; ++j)
      acc += Xs[r * IN_DIM + j] * Ws[j * OUT_DIM + c];
    const size_t idx = (size_t)(row0 + r) * OUT_DIM + c;
    Y[idx] = acc;
    unsigned u = __float_as_uint(acc);
    u += 0x7fffu + ((u >> 16) & 1u);      // round-to-nearest-even bf16
    Yh[idx] = (unsigned short)(u >> 16);
  }
}

// ---------------- degrees: op/seq via direct atomics, machine via LDS hist flush ----------------
__global__ __launch_bounds__(512) void hist_kernel(
    const int* __restrict__ Eseq, const int* __restrict__ Eop2m,
    int* __restrict__ degOp, int* __restrict__ degSeq, int* __restrict__ degM) {
  __shared__ int h[N_M];   // 8 KB
  for (int i = threadIdx.x; i < N_M; i += 512) h[i] = 0;
  __syncthreads();
  const int stride = gridDim.x * 512;
  const int i0 = blockIdx.x * 512 + threadIdx.x;
  for (int e = i0; e < E_OP2M_N; e += stride) {
    atomicAdd(&degOp[Eop2m[e]], 1);
    atomicAdd(&h[Eop2m[E_OP2M_N + e]], 1);
  }
  for (int e = i0; e < E_SEQ_N; e += stride)
    atomicAdd(&degSeq[Eseq[E_SEQ_N + e]], 1);
  __syncthreads();
  for (int i = threadIdx.x; i < N_M; i += 512) {
    const int c = h[i];
    if (c) atomicAdd(&degM[i], c);
  }
}

// ---------------- baseM: exclusive scan of degM (2000 elems, 1 block) ----------------
__global__ __launch_bounds__(256) void scanM_kernel(
    const int* __restrict__ degM, int* __restrict__ baseM) {
  __shared__ int s[256];
  const int t = threadIdx.x;
  int v[8];
  int sum = 0;
  #pragma unroll
  for (int k = 0; k < 8; ++k) {
    const int i = t * 8 + k;
    v[k] = (i < N_M) ? degM[i] : 0;
    sum += v[k];
  }
  s[t] = sum;
  __syncthreads();
  for (int d = 1; d < 256; d <<= 1) {
    const int x = s[t];
    const int y = (t >= d) ? s[t - d] : 0;
    __syncthreads();
    s[t] = x + y;
    __syncthreads();
  }
  int run = s[t] - sum;
  #pragma unroll
  for (int k = 0; k < 8; ++k) {
    const int i = t * 8 + k;
    if (i < N_M) baseM[i] = run;
    run += v[k];
  }
}

// ---------------- Hierarchical exclusive scan over [degOp|degSeq] ----------------
__global__ __launch_bounds__(256) void scanA_kernel(
    const int* __restrict__ in, int* __restrict__ out, int* __restrict__ blockSums, int n) {
  __shared__ int s[256];
  const int base = blockIdx.x * 1024 + threadIdx.x * 4;
  int v[4];
  #pragma unroll
  for (int k = 0; k < 4; ++k) v[k] = (base + k < n) ? in[base + k] : 0;
  const int tsum = v[0] + v[1] + v[2] + v[3];
  s[threadIdx.x] = tsum;
  __syncthreads();
  for (int d = 1; d < 256; d <<= 1) {
    const int x = s[threadIdx.x];
    const int y = (threadIdx.x >= d) ? s[threadIdx.x - d] : 0;
    __syncthreads();
    s[threadIdx.x] = x + y;
    __syncthreads();
  }
  int run = s[threadIdx.x] - tsum;
  if (threadIdx.x == 255) blockSums[blockIdx.x] = s[255];
  #pragma unroll
  for (int k = 0; k < 4; ++k) {
    if (base + k < n) out[base + k] = run;
    run += v[k];
  }
}

__global__ __launch_bounds__(256) void scanB_kernel(int* __restrict__ bs, int nb) {
  __shared__ int s[256];
  const int t = threadIdx.x;
  const int v = (t < nb) ? bs[t] : 0;
  s[t] = v;
  __syncthreads();
  for (int d = 1; d < 256; d <<= 1) {
    const int x = s[t];
    const int y = (t >= d) ? s[t - d] : 0;
    __syncthreads();
    s[t] = x + y;
    __syncthreads();
  }
  if (t < nb) bs[t] = s[t] - v;
}

__global__ __launch_bounds__(256) void scanC_kernel(
    int* __restrict__ out, const int* __restrict__ bs, int n) {
  const int base = blockIdx.x * 1024 + threadIdx.x * 4;
  const int add = bs[blockIdx.x];
  #pragma unroll
  for (int k = 0; k < 4; ++k)
    if (base + k < n) out[base + k] += add;
}

// ---------------- Destination-range-partitioned adjacency fills ----------------
// Group r = blockIdx&7 owns op range [r*12500,..), m range [r*250,..), seq-dst = op range.
// All writes (and cursor atomics) for a given destination line come from one group,
// concentrating them in one XCD's L2 (dispatch round-robin heuristic) -> minimal write-amp.
__global__ __launch_bounds__(256) void fill_part_kernel(
    const int* __restrict__ Eseq, const int* __restrict__ Eop2m,
    const int* __restrict__ S, const int* __restrict__ baseM,
    int* __restrict__ curOp, int* __restrict__ curSeq, int* __restrict__ curM,
    unsigned short* __restrict__ opLu, int* __restrict__ mL, int* __restrict__ seqL) {
  const int grp      = blockIdx.x & (NGRP - 1);
  const int blkInGrp = blockIdx.x >> 3;
  const int nBlkGrp  = gridDim.x >> 3;
  const int tid      = blkInGrp * 256 + threadIdx.x;
  const int gstride  = nBlkGrp * 256;
  const int opLo = grp * OP_PER_GRP, opHi = opLo + OP_PER_GRP;
  const int mLo  = grp * M_PER_GRP,  mHi  = mLo + M_PER_GRP;

  for (int e = tid; e < E_OP2M_N; e += gstride) {
    const int op = Eop2m[e];
    const int m  = Eop2m[E_OP2M_N + e];
    if (op >= opLo && op < opHi)
      opLu[S[op] + atomicAdd(&curOp[op], 1)] = (unsigned short)m;
    if (m >= mLo && m < mHi)
      mL[baseM[m] + atomicAdd(&curM[m], 1)] = op;
  }
  for (int e = tid; e < E_SEQ_N; e += gstride) {
    const int dst = Eseq[E_SEQ_N + e];
    if (dst >= opLo && dst < opHi) {
      const int src = Eseq[e];
      seqL[(S[OFF_SEQ2 + dst] - E_OP2M_N) + atomicAdd(&curSeq[dst], 1)] = src;
    }
  }
}

// ---------------- op output: one wave per op node, fully fused ----------------
// Self row fp32 (residual base); seq + machine gathers bf16.
__global__ __launch_bounds__(256) void op_out_kernel(
    const float* __restrict__ HopProj, const unsigned short* __restrict__ HopProjH,
    const unsigned short* __restrict__ HmProjH,
    const int* __restrict__ S, const unsigned short* __restrict__ opLu,
    const int* __restrict__ seqL, float* __restrict__ out) {
  const int wid = (blockIdx.x * 256 + threadIdx.x) >> 6;
  if (wid >= N_OP) return;
  const int lane = threadIdx.x & 63;
  const int i = wid;
  float2 acc = *reinterpret_cast<const float2*>(HopProj + (size_t)i * OUT_DIM + lane * 2);

  // seq aggregation (mean over incoming seq edges), bf16 rows
  const int s0 = S[OFF_SEQ2 + i] - E_OP2M_N;
  const int s1 = S[OFF_SEQ2 + i + 1] - E_OP2M_N;
  float2 a = make_float2(0.f, 0.f);
  for (int e = s0; e < s1; ++e) {
    const int src = seqL[e];
    const ushort2 h = *reinterpret_cast<const ushort2*>(HopProjH + (size_t)src * OUT_DIM + lane * 2);
    a.x += bf2f(h.x); a.y += bf2f(h.y);
  }
  const float wS = 1.0f / (float)max(s1 - s0, 1);
  acc.x += a.x * wS; acc.y += a.y * wS;

  // machine aggregation (mean of HmProj over incident op2m edges), bf16 rows (L2-resident)
  const int o0 = S[i];
  const int o1 = S[i + 1];
  float2 b = make_float2(0.f, 0.f);
  int e = o0;
  for (; e + 4 <= o1; e += 4) {
    const int m0 = opLu[e];
    const int m1 = opLu[e + 1];
    const int m2 = opLu[e + 2];
    const int m3 = opLu[e + 3];
    const ushort2 h0 = *reinterpret_cast<const ushort2*>(HmProjH + (size_t)m0 * OUT_DIM + lane * 2);
    const ushort2 h1 = *reinterpret_cast<const ushort2*>(HmProjH + (size_t)m1 * OUT_DIM + lane * 2);
    const ushort2 h2 = *reinterpret_cast<const ushort2*>(HmProjH + (size_t)m2 * OUT_DIM + lane * 2);
    const ushort2 h3 = *reinterpret_cast<const ushort2*>(HmProjH + (size_t)m3 * OUT_DIM + lane * 2);
    b.x += (bf2f(h0.x) + bf2f(h1.x)) + (bf2f(h2.x) + bf2f(h3.x));
    b.y += (bf2f(h0.y) + bf2f(h1.y)) + (bf2f(h2.y) + bf2f(h3.y));
  }
  for (; e < o1; ++e) {
    const int m0 = opLu[e];
    const ushort2 h0 = *reinterpret_cast<const ushort2*>(HmProjH + (size_t)m0 * OUT_DIM + lane * 2);
    b.x += bf2f(h0.x); b.y += bf2f(h0.y);
  }
  const float wO = 1.0f / (float)max(o1 - o0, 1);
  acc.x = fmaxf(acc.x + b.x * wO, 0.f);
  acc.y = fmaxf(acc.y + b.y * wO, 0.f);
  *reinterpret_cast<float2*>(out + (size_t)i * OUT_DIM + lane * 2) = acc;
}

// ---------------- machine output: bf16 gather (256 B/row), fp32 accumulate ----------------
__global__ __launch_bounds__(512) void m_out_kernel(
    const unsigned short* __restrict__ HopProjH, const float* __restrict__ HmProj,
    const int* __restrict__ mL, const int* __restrict__ baseM, const int* __restrict__ degM,
    float* __restrict__ outM) {
  __shared__ float red[16][129];    // 129 pad: conflict-free column reads in reduce
  const int m = blockIdx.x;
  const int s0 = baseM[m];
  const int deg = degM[m];
  const int c4   = (threadIdx.x & 31) << 2;   // column base 0..124
  const int slot = threadIdx.x >> 5;          // 0..15
  float ax = 0.f, ay = 0.f, az = 0.f, aw = 0.f;
  int e = slot;
  for (; e + 48 < deg; e += 64) {
    const int o0 = mL[s0 + e];
    const int o1 = mL[s0 + e + 16];
    const int o2 = mL[s0 + e + 32];
    const int o3 = mL[s0 + e + 48];
    const ushort4 h0 = *reinterpret_cast<const ushort4*>(HopProjH + (size_t)o0 * OUT_DIM + c4);
    const ushort4 h1 = *reinterpret_cast<const ushort4*>(HopProjH + (size_t)o1 * OUT_DIM + c4);
    const ushort4 h2 = *reinterpret_cast<const ushort4*>(HopProjH + (size_t)o2 * OUT_DIM + c4);
    const ushort4 h3 = *reinterpret_cast<const ushort4*>(HopProjH + (size_t)o3 * OUT_DIM + c4);
    ax += (bf2f(h0.x) + bf2f(h1.x)) + (bf2f(h2.x) + bf2f(h3.x));
    ay += (bf2f(h0.y) + bf2f(h1.y)) + (bf2f(h2.y) + bf2f(h3.y));
    az += (bf2f(h0.z) + bf2f(h1.z)) + (bf2f(h2.z) + bf2f(h3.z));
    aw += (bf2f(h0.w) + bf2f(h1.w)) + (bf2f(h2.w) + bf2f(h3.w));
  }
  for (; e < deg; e += 16) {
    const int o = mL[s0 + e];
    const ushort4 h = *reinterpret_cast<const ushort4*>(HopProjH + (size_t)o * OUT_DIM + c4);
    ax += bf2f(h.x); ay += bf2f(h.y); az += bf2f(h.z); aw += bf2f(h.w);
  }
  red[slot][c4 + 0] = ax;
  red[slot][c4 + 1] = ay;
  red[slot][c4 + 2] = az;
  red[slot][c4 + 3] = aw;
  __syncthreads();
  if (threadIdx.x < 128) {
    const int col = threadIdx.x;
    float s = 0.f;
    #pragma unroll
    for (int k = 0; k < 16; ++k) s += red[k][col];
    const float v = HmProj[m * OUT_DIM + col] + s / (float)max(deg, 1);
    outM[m * OUT_DIM + col] = fmaxf(v, 0.f);
  }
}

extern "C" void kernel_launch(void* const* d_in, const int* in_sizes, int n_in,
                              void* d_out, int out_size, void* d_ws, size_t ws_size,
                              hipStream_t stream) {
  const float* H_op   = (const float*)d_in[0];
  const float* H_m    = (const float*)d_in[1];
  const int*   E_seq  = (const int*)d_in[2];
  const int*   E_op2m = (const int*)d_in[3];
  const float* W_op   = (const float*)d_in[4];
  const float* b_op   = (const float*)d_in[5];
  const float* W_m    = (const float*)d_in[6];
  const float* b_m    = (const float*)d_in[7];
  float* out = (float*)d_out;

  // ---- workspace layout (element offsets, 4B units unless noted) ----
  float* HopProj = (float*)d_ws;                                // 12,800,000
  float* HmProj  = HopProj + (size_t)N_OP * OUT_DIM;            //    256,000
  // zeroed region (contiguous): degOp|degSeq|curOp|curSeq|degM|curM
  int*   degOp   = (int*)(HmProj + (size_t)N_M * OUT_DIM);      //    100,000
  int*   degSeq  = degOp + N_OP;                                //    100,000
  int*   curOp   = degSeq + N_OP;                               //    100,000
  int*   curSeq  = curOp + N_OP;                                //    100,000
  int*   degM    = curSeq + N_OP;                               //      2,048
  int*   curM    = degM + 2048;                                 //      2,048
  // end zeroed region
  int*   baseM   = curM + 2048;                                 //      2,048
  int*   S       = baseM + 2048;                                //    200,704
  int*   bsums   = S + 200704;                                  //        512
  unsigned short* opLu = (unsigned short*)(bsums + 512);        //  2,000,000 ushort (1M int)
  int*   mL      = (int*)(opLu + E_OP2M_N);                     //  2,000,000
  int*   seqL    = mL + E_OP2M_N;                               //    100,000
  unsigned short* HopProjH = (unsigned short*)(seqL + E_SEQ_N); // 12,800,000 ushort
  unsigned short* HmProjH  = HopProjH + (size_t)N_OP * OUT_DIM; //    256,000 ushort

  // 1. projections (fp32 + bf16 copies)
  proj_kernel<<<(N_OP + 15) / 16, 256, 0, stream>>>(H_op, W_op, b_op, HopProj, HopProjH, N_OP);
  proj_kernel<<<(N_M + 15) / 16, 256, 0, stream>>>(H_m, W_m, b_m, HmProj, HmProjH, N_M);

  // 2. zero degOp/degSeq/curOp/curSeq/degM/curM (one contiguous memset)
  hipMemsetAsync(degOp, 0, ((size_t)4 * N_OP + 4096) * sizeof(int), stream);

  // 3. degrees (LDS histogram for machines, direct atomics for op/seq)
  hist_kernel<<<512, 512, 0, stream>>>(E_seq, E_op2m, degOp, degSeq, degM);

  // 4. baseM and S scans
  scanM_kernel<<<1, 256, 0, stream>>>(degM, baseM);
  const int nScanBlocks = (SCAN_N2 + 1023) / 1024;   // 196
  scanA_kernel<<<nScanBlocks, 256, 0, stream>>>(degOp, S, bsums, SCAN_N2);
  scanB_kernel<<<1, 256, 0, stream>>>(bsums, nScanBlocks);
  scanC_kernel<<<nScanBlocks, 256, 0, stream>>>(S, bsums, SCAN_N2);

  // 5. destination-range-partitioned fills
  fill_part_kernel<<<2048, 256, 0, stream>>>(E_seq, E_op2m, S, baseM,
                                             curOp, curSeq, curM, opLu, mL, seqL);

  // 6. outputs
  {
    const long long threads = (long long)N_OP * 64;
    op_out_kernel<<<(int)((threads + 255) / 256), 256, 0, stream>>>(
        HopProj, HopProjH, HmProjH, S, opLu, seqL, out);
  }
  m_out_kernel<<<N_M, 512, 0, stream>>>(HopProjH, HmProj, mL, baseM, degM,
                                        out + (size_t)N_OP * OUT_DIM);
}

// Round 9
// 490.323 us; speedup vs baseline: 1.6411x; 1.6411x over previous
//
#include <hip/hip_runtime.h>

// Problem constants (match reference)
constexpr int N_OP    = 100000;
constexpr int N_M     = 2000;
constexpr int IN_DIM  = 64;
constexpr int OUT_DIM = 128;
constexpr int E_SEQ_N  = 100000;
constexpr int E_OP2M_N = 2000000;

// Counting-sort partitioning for the machine axis
constexpr int W_BLK     = 512;                       // partitions of the edge list
constexpr int CHUNK     = (E_OP2M_N + W_BLK - 1) / W_BLK;  // 3907
constexpr int SEQ_CHUNK = (E_SEQ_N + W_BLK - 1) / W_BLK;   // 196

// S layout: scan over [degOp(100000) | degSeq(100000) | trailing 0]
constexpr int OFF_SEQ2 = 100000;
constexpr int SCAN_N2  = 200001;

__device__ __forceinline__ float bf2f(unsigned short h) {
  return __uint_as_float((unsigned)h << 16);
}

// ---------------- Projection: Y[nrows,128] = X[nrows,64] @ W[64,128] + b ----------------
// Emits bf16 (RNE) always; fp32 copy only if Y != nullptr (machines need it for the residual).
__global__ __launch_bounds__(256) void proj_kernel(
    const float* __restrict__ X, const float* __restrict__ W,
    const float* __restrict__ b, float* __restrict__ Y,
    unsigned short* __restrict__ Yh, int nrows) {
  __shared__ float Ws[IN_DIM * OUT_DIM];   // 32 KB
  __shared__ float bs[OUT_DIM];
  __shared__ float Xs[16 * IN_DIM];        // 4 KB
  const int t = threadIdx.x;
  for (int i = t; i < IN_DIM * OUT_DIM; i += 256) Ws[i] = W[i];
  if (t < OUT_DIM) bs[t] = b[t];
  const int row0 = blockIdx.x * 16;
  const int nr = min(16, nrows - row0);
  for (int i = t; i < nr * IN_DIM; i += 256) Xs[i] = X[(size_t)row0 * IN_DIM + i];
  __syncthreads();
  const int c = t & 127;
  #pragma unroll
  for (int k = 0; k < 8; ++k) {
    const int o = t + k * 256;
    const int r = o >> 7;
    if (r >= nr) break;
    float acc = bs[c];
    #pragma unroll
    for (int j = 0; j < IN_DIM; ++j)
      acc += Xs[r * IN_DIM + j] * Ws[j * OUT_DIM + c];
    const size_t idx = (size_t)(row0 + r) * OUT_DIM + c;
    if (Y) Y[idx] = acc;
    unsigned u = __float_as_uint(acc);
    u += 0x7fffu + ((u >> 16) & 1u);      // round-to-nearest-even bf16
    Yh[idx] = (unsigned short)(u >> 16);
  }
}

// ---------------- Phase A: per-block m-histogram + op/seq degree atomics ----------------
__global__ __launch_bounds__(512) void histA_kernel(
    const int* __restrict__ Eseq, const int* __restrict__ Eop2m,
    int* __restrict__ H, int* __restrict__ degOp, int* __restrict__ degSeq) {
  __shared__ int h[N_M];   // 8 KB
  for (int i = threadIdx.x; i < N_M; i += 512) h[i] = 0;
  __syncthreads();
  const int w = blockIdx.x;
  const int e0 = w * CHUNK, e1 = min(E_OP2M_N, e0 + CHUNK);
  for (int e = e0 + threadIdx.x; e < e1; e += 512) {
    atomicAdd(&degOp[Eop2m[e]], 1);
    atomicAdd(&h[Eop2m[E_OP2M_N + e]], 1);
  }
  const int s0 = w * SEQ_CHUNK, s1 = min(E_SEQ_N, s0 + SEQ_CHUNK);
  for (int e = s0 + threadIdx.x; e < s1; e += 512)
    atomicAdd(&degSeq[Eseq[E_SEQ_N + e]], 1);
  __syncthreads();
  for (int i = threadIdx.x; i < N_M; i += 512) H[w * N_M + i] = h[i];
}

// ---------------- Phase B: exclusive column scan of H; degM = column sums ----------------
__global__ __launch_bounds__(512) void colscan_kernel(int* __restrict__ H, int* __restrict__ degM) {
  __shared__ int s[W_BLK];
  const int m = blockIdx.x;
  const int t = threadIdx.x;
  const int v = H[t * N_M + m];
  s[t] = v;
  __syncthreads();
  for (int d = 1; d < W_BLK; d <<= 1) {
    const int x = s[t];
    const int y = (t >= d) ? s[t - d] : 0;
    __syncthreads();
    s[t] = x + y;
    __syncthreads();
  }
  H[t * N_M + m] = s[t] - v;           // exclusive offset of block t within machine m
  if (t == W_BLK - 1) degM[m] = s[W_BLK - 1];
}

// ---------------- baseM: exclusive scan of degM (2000 elems, 1 block) ----------------
__global__ __launch_bounds__(256) void scanM_kernel(
    const int* __restrict__ degM, int* __restrict__ baseM) {
  __shared__ int s[256];
  const int t = threadIdx.x;
  int v[8];
  int sum = 0;
  #pragma unroll
  for (int k = 0; k < 8; ++k) {
    const int i = t * 8 + k;
    v[k] = (i < N_M) ? degM[i] : 0;
    sum += v[k];
  }
  s[t] = sum;
  __syncthreads();
  for (int d = 1; d < 256; d <<= 1) {
    const int x = s[t];
    const int y = (t >= d) ? s[t - d] : 0;
    __syncthreads();
    s[t] = x + y;
    __syncthreads();
  }
  int run = s[t] - sum;
  #pragma unroll
  for (int k = 0; k < 8; ++k) {
    const int i = t * 8 + k;
    if (i < N_M) baseM[i] = run;
    run += v[k];
  }
}

// ---------------- Hierarchical exclusive scan over [degOp|degSeq] ----------------
__global__ __launch_bounds__(256) void scanA_kernel(
    const int* __restrict__ in, int* __restrict__ out, int* __restrict__ blockSums, int n) {
  __shared__ int s[256];
  const int base = blockIdx.x * 1024 + threadIdx.x * 4;
  int v[4];
  #pragma unroll
  for (int k = 0; k < 4; ++k) v[k] = (base + k < n) ? in[base + k] : 0;
  const int tsum = v[0] + v[1] + v[2] + v[3];
  s[threadIdx.x] = tsum;
  __syncthreads();
  for (int d = 1; d < 256; d <<= 1) {
    const int x = s[threadIdx.x];
    const int y = (threadIdx.x >= d) ? s[threadIdx.x - d] : 0;
    __syncthreads();
    s[threadIdx.x] = x + y;
    __syncthreads();
  }
  int run = s[threadIdx.x] - tsum;
  if (threadIdx.x == 255) blockSums[blockIdx.x] = s[255];
  #pragma unroll
  for (int k = 0; k < 4; ++k) {
    if (base + k < n) out[base + k] = run;
    run += v[k];
  }
}

__global__ __launch_bounds__(256) void scanB_kernel(int* __restrict__ bs, int nb) {
  __shared__ int s[256];
  const int t = threadIdx.x;
  const int v = (t < nb) ? bs[t] : 0;
  s[t] = v;
  __syncthreads();
  for (int d = 1; d < 256; d <<= 1) {
    const int x = s[t];
    const int y = (t >= d) ? s[t - d] : 0;
    __syncthreads();
    s[t] = x + y;
    __syncthreads();
  }
  if (t < nb) bs[t] = s[t] - v;
}

__global__ __launch_bounds__(256) void scanC_kernel(
    int* __restrict__ out, const int* __restrict__ bs, int n) {
  const int base = blockIdx.x * 1024 + threadIdx.x * 4;
  const int add = bs[blockIdx.x];
  #pragma unroll
  for (int k = 0; k < 4; ++k)
    if (base + k < n) out[base + k] += add;
}

// ---------------- Fill all three adjacency lists (merged, 512 threads) ----------------
// mL via counting-sort offsets (LDS cursors only); opLu/seqL via low-contention cursors.
__global__ __launch_bounds__(512) void fill_kernel(
    const int* __restrict__ Eseq, const int* __restrict__ Eop2m,
    const int* __restrict__ S, const int* __restrict__ H, const int* __restrict__ baseM,
    int* __restrict__ curOp, int* __restrict__ curSeq,
    unsigned short* __restrict__ opLu, int* __restrict__ mL, int* __restrict__ seqL) {
  __shared__ int lcur[N_M];   // 8 KB
  for (int i = threadIdx.x; i < N_M; i += 512) lcur[i] = 0;
  __syncthreads();
  const int w = blockIdx.x;
  const int base = w * N_M;
  const int e0 = w * CHUNK, e1 = min(E_OP2M_N, e0 + CHUNK);
  for (int e = e0 + threadIdx.x; e < e1; e += 512) {
    const int op = Eop2m[e];
    const int m  = Eop2m[E_OP2M_N + e];
    opLu[S[op] + atomicAdd(&curOp[op], 1)] = (unsigned short)m;
    mL[baseM[m] + H[base + m] + atomicAdd(&lcur[m], 1)] = op;
  }
  const int s0 = w * SEQ_CHUNK, s1 = min(E_SEQ_N, s0 + SEQ_CHUNK);
  for (int e = s0 + threadIdx.x; e < s1; e += 512) {
    const int src = Eseq[e];
    const int dst = Eseq[E_SEQ_N + e];
    seqL[(S[OFF_SEQ2 + dst] - E_OP2M_N) + atomicAdd(&curSeq[dst], 1)] = src;
  }
}

// ---------------- op output: one wave per op node, fully fused, all-bf16 reads ----------------
__global__ __launch_bounds__(256) void op_out_kernel(
    const unsigned short* __restrict__ HopProjH, const unsigned short* __restrict__ HmProjH,
    const int* __restrict__ S, const unsigned short* __restrict__ opLu,
    const int* __restrict__ seqL, float* __restrict__ out) {
  const int wid = (blockIdx.x * 256 + threadIdx.x) >> 6;
  if (wid >= N_OP) return;
  const int lane = threadIdx.x & 63;
  const int i = wid;
  const ushort2 hself = *reinterpret_cast<const ushort2*>(HopProjH + (size_t)i * OUT_DIM + lane * 2);
  float2 acc = make_float2(bf2f(hself.x), bf2f(hself.y));

  // seq aggregation (mean over incoming seq edges), bf16 rows
  const int s0 = S[OFF_SEQ2 + i] - E_OP2M_N;
  const int s1 = S[OFF_SEQ2 + i + 1] - E_OP2M_N;
  float2 a = make_float2(0.f, 0.f);
  for (int e = s0; e < s1; ++e) {
    const int src = seqL[e];
    const ushort2 h = *reinterpret_cast<const ushort2*>(HopProjH + (size_t)src * OUT_DIM + lane * 2);
    a.x += bf2f(h.x); a.y += bf2f(h.y);
  }
  const float wS = 1.0f / (float)max(s1 - s0, 1);
  acc.x += a.x * wS; acc.y += a.y * wS;

  // machine aggregation (mean of HmProj over incident op2m edges), bf16 rows (L2-resident)
  const int o0 = S[i];
  const int o1 = S[i + 1];
  float2 b = make_float2(0.f, 0.f);
  int e = o0;
  for (; e + 4 <= o1; e += 4) {
    const int m0 = opLu[e];
    const int m1 = opLu[e + 1];
    const int m2 = opLu[e + 2];
    const int m3 = opLu[e + 3];
    const ushort2 h0 = *reinterpret_cast<const ushort2*>(HmProjH + (size_t)m0 * OUT_DIM + lane * 2);
    const ushort2 h1 = *reinterpret_cast<const ushort2*>(HmProjH + (size_t)m1 * OUT_DIM + lane * 2);
    const ushort2 h2 = *reinterpret_cast<const ushort2*>(HmProjH + (size_t)m2 * OUT_DIM + lane * 2);
    const ushort2 h3 = *reinterpret_cast<const ushort2*>(HmProjH + (size_t)m3 * OUT_DIM + lane * 2);
    b.x += (bf2f(h0.x) + bf2f(h1.x)) + (bf2f(h2.x) + bf2f(h3.x));
    b.y += (bf2f(h0.y) + bf2f(h1.y)) + (bf2f(h2.y) + bf2f(h3.y));
  }
  for (; e < o1; ++e) {
    const int m0 = opLu[e];
    const ushort2 h0 = *reinterpret_cast<const ushort2*>(HmProjH + (size_t)m0 * OUT_DIM + lane * 2);
    b.x += bf2f(h0.x); b.y += bf2f(h0.y);
  }
  const float wO = 1.0f / (float)max(o1 - o0, 1);
  acc.x = fmaxf(acc.x + b.x * wO, 0.f);
  acc.y = fmaxf(acc.y + b.y * wO, 0.f);
  *reinterpret_cast<float2*>(out + (size_t)i * OUT_DIM + lane * 2) = acc;
}

// ---------------- machine output: bf16 gather (256 B/row), fp32 accumulate ----------------
__global__ __launch_bounds__(512) void m_out_kernel(
    const unsigned short* __restrict__ HopProjH, const float* __restrict__ HmProj,
    const int* __restrict__ mL, const int* __restrict__ baseM, const int* __restrict__ degM,
    float* __restrict__ outM) {
  __shared__ float red[16][129];    // 129 pad: conflict-free column reads in reduce
  const int m = blockIdx.x;
  const int s0 = baseM[m];
  const int deg = degM[m];
  const int c4   = (threadIdx.x & 31) << 2;   // column base 0..124
  const int slot = threadIdx.x >> 5;          // 0..15
  float ax = 0.f, ay = 0.f, az = 0.f, aw = 0.f;
  int e = slot;
  for (; e + 48 < deg; e += 64) {
    const int o0 = mL[s0 + e];
    const int o1 = mL[s0 + e + 16];
    const int o2 = mL[s0 + e + 32];
    const int o3 = mL[s0 + e + 48];
    const ushort4 h0 = *reinterpret_cast<const ushort4*>(HopProjH + (size_t)o0 * OUT_DIM + c4);
    const ushort4 h1 = *reinterpret_cast<const ushort4*>(HopProjH + (size_t)o1 * OUT_DIM + c4);
    const ushort4 h2 = *reinterpret_cast<const ushort4*>(HopProjH + (size_t)o2 * OUT_DIM + c4);
    const ushort4 h3 = *reinterpret_cast<const ushort4*>(HopProjH + (size_t)o3 * OUT_DIM + c4);
    ax += (bf2f(h0.x) + bf2f(h1.x)) + (bf2f(h2.x) + bf2f(h3.x));
    ay += (bf2f(h0.y) + bf2f(h1.y)) + (bf2f(h2.y) + bf2f(h3.y));
    az += (bf2f(h0.z) + bf2f(h1.z)) + (bf2f(h2.z) + bf2f(h3.z));
    aw += (bf2f(h0.w) + bf2f(h1.w)) + (bf2f(h2.w) + bf2f(h3.w));
  }
  for (; e < deg; e += 16) {
    const int o = mL[s0 + e];
    const ushort4 h = *reinterpret_cast<const ushort4*>(HopProjH + (size_t)o * OUT_DIM + c4);
    ax += bf2f(h.x); ay += bf2f(h.y); az += bf2f(h.z); aw += bf2f(h.w);
  }
  red[slot][c4 + 0] = ax;
  red[slot][c4 + 1] = ay;
  red[slot][c4 + 2] = az;
  red[slot][c4 + 3] = aw;
  __syncthreads();
  if (threadIdx.x < 128) {
    const int col = threadIdx.x;
    float s = 0.f;
    #pragma unroll
    for (int k = 0; k < 16; ++k) s += red[k][col];
    const float v = HmProj[m * OUT_DIM + col] + s / (float)max(deg, 1);
    outM[m * OUT_DIM + col] = fmaxf(v, 0.f);
  }
}

extern "C" void kernel_launch(void* const* d_in, const int* in_sizes, int n_in,
                              void* d_out, int out_size, void* d_ws, size_t ws_size,
                              hipStream_t stream) {
  const float* H_op   = (const float*)d_in[0];
  const float* H_m    = (const float*)d_in[1];
  const int*   E_seq  = (const int*)d_in[2];
  const int*   E_op2m = (const int*)d_in[3];
  const float* W_op   = (const float*)d_in[4];
  const float* b_op   = (const float*)d_in[5];
  const float* W_m    = (const float*)d_in[6];
  const float* b_m    = (const float*)d_in[7];
  float* out = (float*)d_out;

  // ---- workspace layout (element offsets, 4B units unless noted) ----
  float* HmProj  = (float*)d_ws;                                //    256,000
  int*   degOp   = (int*)(HmProj + (size_t)N_M * OUT_DIM);      //    100,000 (zeroed)
  int*   degSeq  = degOp + N_OP;                                //    100,000 (zeroed)
  int*   curOp   = degSeq + N_OP;                               //    100,000 (zeroed)
  int*   curSeq  = curOp + N_OP;                                //    100,000 (zeroed)
  int*   degM    = curSeq + N_OP;                               //      2,048
  int*   baseM   = degM + 2048;                                 //      2,048
  int*   S       = baseM + 2048;                                //    200,704
  int*   bsums   = S + 200704;                                  //        512
  int*   Hh      = bsums + 512;                                 //  1,024,000 (W_BLK * N_M)
  unsigned short* opLu = (unsigned short*)(Hh + (size_t)W_BLK * N_M); // 2,000,000 ushort
  int*   mL      = (int*)(opLu + E_OP2M_N);                     //  2,000,000
  int*   seqL    = mL + E_OP2M_N;                               //    100,000
  unsigned short* HopProjH = (unsigned short*)(seqL + E_SEQ_N); // 12,800,000 ushort
  unsigned short* HmProjH  = HopProjH + (size_t)N_OP * OUT_DIM; //    256,000 ushort

  // 1. projections (ops: bf16 only; machines: fp32 + bf16)
  proj_kernel<<<(N_OP + 15) / 16, 256, 0, stream>>>(H_op, W_op, b_op, nullptr, HopProjH, N_OP);
  proj_kernel<<<(N_M + 15) / 16, 256, 0, stream>>>(H_m, W_m, b_m, HmProj, HmProjH, N_M);

  // 2. zero degOp/degSeq/curOp/curSeq (contiguous)
  hipMemsetAsync(degOp, 0, (size_t)4 * N_OP * sizeof(int), stream);

  // 3. machine histograms + op/seq degrees
  histA_kernel<<<W_BLK, 512, 0, stream>>>(E_seq, E_op2m, Hh, degOp, degSeq);

  // 4. column scan of H -> per-block offsets + degM; then baseM
  colscan_kernel<<<N_M, W_BLK, 0, stream>>>(Hh, degM);
  scanM_kernel<<<1, 256, 0, stream>>>(degM, baseM);

  // 5. exclusive scan of [degOp|degSeq] -> S
  const int nScanBlocks = (SCAN_N2 + 1023) / 1024;   // 196
  scanA_kernel<<<nScanBlocks, 256, 0, stream>>>(degOp, S, bsums, SCAN_N2);
  scanB_kernel<<<1, 256, 0, stream>>>(bsums, nScanBlocks);
  scanC_kernel<<<nScanBlocks, 256, 0, stream>>>(S, bsums, SCAN_N2);

  // 6. fill adjacency lists (merged, 512 threads)
  fill_kernel<<<W_BLK, 512, 0, stream>>>(E_seq, E_op2m, S, Hh, baseM,
                                         curOp, curSeq, opLu, mL, seqL);

  // 7. outputs
  {
    const long long threads = (long long)N_OP * 64;
    op_out_kernel<<<(int)((threads + 255) / 256), 256, 0, stream>>>(
        HopProjH, HmProjH, S, opLu, seqL, out);
  }
  m_out_kernel<<<N_M, 512, 0, stream>>>(HopProjH, HmProj, mL, baseM, degM,
                                        out + (size_t)N_OP * OUT_DIM);
}

// Round 10
// 393.270 us; speedup vs baseline: 2.0461x; 1.2468x over previous
//
#include <hip/hip_runtime.h>

// Problem constants (match reference)
constexpr int N_OP    = 100000;
constexpr int N_M     = 2000;
constexpr int IN_DIM  = 64;
constexpr int OUT_DIM = 128;
constexpr int E_SEQ_N  = 100000;
constexpr int E_OP2M_N = 2000000;

// S layout: scan over [degOp(100000) | degSeq(100000) | trailing 0]
constexpr int OFF_SEQ2 = 100000;
constexpr int SCAN_N2  = 200001;

// op-range bucketing: bucket = op >> 8 (256 ops per bucket)
constexpr int OPB_SHIFT = 8;
constexpr int OPB       = 256;
constexpr int NBKT      = (N_OP + OPB - 1) / OPB;   // 391
constexpr int BKT_BLOCKS = 256;
constexpr int BKT_CHUNK  = (E_OP2M_N + BKT_BLOCKS - 1) / BKT_BLOCKS;  // 7813
constexpr int FM_BLOCKS  = 128;
constexpr int FM_CHUNK   = (E_OP2M_N + FM_BLOCKS - 1) / FM_BLOCKS;    // 15625
constexpr int SMCAP      = 8192;   // per-bucket edge capacity in op_out_b LDS (mean 5120, sigma ~72)

__device__ __forceinline__ float bf2f(unsigned short h) {
  return __uint_as_float((unsigned)h << 16);
}

// ---------------- Projection: Y[nrows,128] = X[nrows,64] @ W[64,128] + b ----------------
// Emits bf16 (RNE) always; fp32 copy only if Y != nullptr (machines need it for the residual).
__global__ __launch_bounds__(256) void proj_kernel(
    const float* __restrict__ X, const float* __restrict__ W,
    const float* __restrict__ b, float* __restrict__ Y,
    unsigned short* __restrict__ Yh, int nrows) {
  __shared__ float Ws[IN_DIM * OUT_DIM];   // 32 KB
  __shared__ float bs[OUT_DIM];
  __shared__ float Xs[16 * IN_DIM];        // 4 KB
  const int t = threadIdx.x;
  for (int i = t; i < IN_DIM * OUT_DIM; i += 256) Ws[i] = W[i];
  if (t < OUT_DIM) bs[t] = b[t];
  const int row0 = blockIdx.x * 16;
  const int nr = min(16, nrows - row0);
  for (int i = t; i < nr * IN_DIM; i += 256) Xs[i] = X[(size_t)row0 * IN_DIM + i];
  __syncthreads();
  const int c = t & 127;
  #pragma unroll
  for (int k = 0; k < 8; ++k) {
    const int o = t + k * 256;
    const int r = o >> 7;
    if (r >= nr) break;
    float acc = bs[c];
    #pragma unroll
    for (int j = 0; j < IN_DIM; ++j)
      acc += Xs[r * IN_DIM + j] * Ws[j * OUT_DIM + c];
    const size_t idx = (size_t)(row0 + r) * OUT_DIM + c;
    if (Y) Y[idx] = acc;
    unsigned u = __float_as_uint(acc);
    u += 0x7fffu + ((u >> 16) & 1u);      // round-to-nearest-even bf16
    Yh[idx] = (unsigned short)(u >> 16);
  }
}

// ---------------- degrees: op/seq via global atomics; machine via LDS hist flush ----------------
__global__ __launch_bounds__(512) void hist_kernel(
    const int* __restrict__ Eseq, const int* __restrict__ Eop2m,
    int* __restrict__ degOp, int* __restrict__ degSeq, int* __restrict__ degM) {
  __shared__ int h[N_M];   // 8 KB
  for (int i = threadIdx.x; i < N_M; i += 512) h[i] = 0;
  __syncthreads();
  const int stride = gridDim.x * 512;
  const int i0 = blockIdx.x * 512 + threadIdx.x;
  for (int e = i0; e < E_OP2M_N; e += stride) {
    atomicAdd(&degOp[Eop2m[e]], 1);
    atomicAdd(&h[Eop2m[E_OP2M_N + e]], 1);
  }
  for (int e = i0; e < E_SEQ_N; e += stride)
    atomicAdd(&degSeq[Eseq[E_SEQ_N + e]], 1);
  __syncthreads();
  for (int i = threadIdx.x; i < N_M; i += 512) {
    const int c = h[i];
    if (c) atomicAdd(&degM[i], c);
  }
}

// ---------------- baseM: exclusive scan of degM (2000 elems, 1 block) ----------------
__global__ __launch_bounds__(256) void scanM_kernel(
    const int* __restrict__ degM, int* __restrict__ baseM) {
  __shared__ int s[256];
  const int t = threadIdx.x;
  int v[8];
  int sum = 0;
  #pragma unroll
  for (int k = 0; k < 8; ++k) {
    const int i = t * 8 + k;
    v[k] = (i < N_M) ? degM[i] : 0;
    sum += v[k];
  }
  s[t] = sum;
  __syncthreads();
  for (int d = 1; d < 256; d <<= 1) {
    const int x = s[t];
    const int y = (t >= d) ? s[t - d] : 0;
    __syncthreads();
    s[t] = x + y;
    __syncthreads();
  }
  int run = s[t] - sum;
  #pragma unroll
  for (int k = 0; k < 8; ++k) {
    const int i = t * 8 + k;
    if (i < N_M) baseM[i] = run;
    run += v[k];
  }
}

// ---------------- Hierarchical exclusive scan over [degOp|degSeq] ----------------
__global__ __launch_bounds__(256) void scanA_kernel(
    const int* __restrict__ in, int* __restrict__ out, int* __restrict__ blockSums, int n) {
  __shared__ int s[256];
  const int base = blockIdx.x * 1024 + threadIdx.x * 4;
  int v[4];
  #pragma unroll
  for (int k = 0; k < 4; ++k) v[k] = (base + k < n) ? in[base + k] : 0;
  const int tsum = v[0] + v[1] + v[2] + v[3];
  s[threadIdx.x] = tsum;
  __syncthreads();
  for (int d = 1; d < 256; d <<= 1) {
    const int x = s[threadIdx.x];
    const int y = (threadIdx.x >= d) ? s[threadIdx.x - d] : 0;
    __syncthreads();
    s[threadIdx.x] = x + y;
    __syncthreads();
  }
  int run = s[threadIdx.x] - tsum;
  if (threadIdx.x == 255) blockSums[blockIdx.x] = s[255];
  #pragma unroll
  for (int k = 0; k < 4; ++k) {
    if (base + k < n) out[base + k] = run;
    run += v[k];
  }
}

__global__ __launch_bounds__(256) void scanB_kernel(int* __restrict__ bs, int nb) {
  __shared__ int s[256];
  const int t = threadIdx.x;
  const int v = (t < nb) ? bs[t] : 0;
  s[t] = v;
  __syncthreads();
  for (int d = 1; d < 256; d <<= 1) {
    const int x = s[t];
    const int y = (t >= d) ? s[t - d] : 0;
    __syncthreads();
    s[t] = x + y;
    __syncthreads();
  }
  if (t < nb) bs[t] = s[t] - v;
}

__global__ __launch_bounds__(256) void scanC_kernel(
    int* __restrict__ out, const int* __restrict__ bs, int n) {
  const int base = blockIdx.x * 1024 + threadIdx.x * 4;
  const int add = bs[blockIdx.x];
  #pragma unroll
  for (int k = 0; k < 4; ++k)
    if (base + k < n) out[base + k] += add;
}

// ---------------- bucket fill: pack (op<<11|m) into op-range buckets ----------------
// hist -> per-(block,bucket) reservation -> scatter into ~80B contiguous runs.
__global__ __launch_bounds__(512) void fill_bkt_kernel(
    const int* __restrict__ Eop2m, const int* __restrict__ S,
    int* __restrict__ bktCur, unsigned* __restrict__ bktArr) {
  __shared__ int h[NBKT], ofs[NBKT], lcur[NBKT];
  for (int i = threadIdx.x; i < NBKT; i += 512) { h[i] = 0; lcur[i] = 0; }
  __syncthreads();
  const int e0 = blockIdx.x * BKT_CHUNK;
  const int e1 = min(E_OP2M_N, e0 + BKT_CHUNK);
  for (int e = e0 + threadIdx.x; e < e1; e += 512)
    atomicAdd(&h[Eop2m[e] >> OPB_SHIFT], 1);
  __syncthreads();
  for (int t = threadIdx.x; t < NBKT; t += 512)
    ofs[t] = atomicAdd(&bktCur[t], h[t]);
  __syncthreads();
  for (int e = e0 + threadIdx.x; e < e1; e += 512) {
    const int op = Eop2m[e];
    const int m  = Eop2m[E_OP2M_N + e];
    const int b  = op >> OPB_SHIFT;
    const int p  = S[b << OPB_SHIFT] + ofs[b] + atomicAdd(&lcur[b], 1);
    bktArr[p] = ((unsigned)op << 11) | (unsigned)m;
  }
}

// ---------------- mL fill: hist -> reservation -> scatter (m axis) + seqL tail ----------------
__global__ __launch_bounds__(1024) void fill_m_kernel(
    const int* __restrict__ Eseq, const int* __restrict__ Eop2m,
    const int* __restrict__ S, const int* __restrict__ baseM,
    int* __restrict__ curM, int* __restrict__ curSeq,
    int* __restrict__ mL, int* __restrict__ seqL) {
  __shared__ int h[N_M], ofs[N_M], lcur[N_M];   // 24 KB
  for (int i = threadIdx.x; i < N_M; i += 1024) { h[i] = 0; lcur[i] = 0; }
  __syncthreads();
  const int e0 = blockIdx.x * FM_CHUNK;
  const int e1 = min(E_OP2M_N, e0 + FM_CHUNK);
  for (int e = e0 + threadIdx.x; e < e1; e += 1024)
    atomicAdd(&h[Eop2m[E_OP2M_N + e]], 1);
  __syncthreads();
  for (int t = threadIdx.x; t < N_M; t += 1024)
    ofs[t] = atomicAdd(&curM[t], h[t]);
  __syncthreads();
  for (int e = e0 + threadIdx.x; e < e1; e += 1024) {
    const int op = Eop2m[e];
    const int m  = Eop2m[E_OP2M_N + e];
    mL[baseM[m] + ofs[m] + atomicAdd(&lcur[m], 1)] = op;
  }
  // seqL cursor scatter (small: 100K edges)
  const int stride = gridDim.x * 1024;
  for (int e = blockIdx.x * 1024 + threadIdx.x; e < E_SEQ_N; e += stride) {
    const int src = Eseq[e];
    const int dst = Eseq[E_SEQ_N + e];
    seqL[(S[OFF_SEQ2 + dst] - E_OP2M_N) + atomicAdd(&curSeq[dst], 1)] = src;
  }
}

// ---------------- op output: one block per bucket; in-LDS sort by op, then gather ----------------
__global__ __launch_bounds__(1024) void op_out_b_kernel(
    const unsigned* __restrict__ bktArr, const unsigned short* __restrict__ HopProjH,
    const unsigned short* __restrict__ HmProjH, const int* __restrict__ S,
    const int* __restrict__ seqL, float* __restrict__ out) {
  __shared__ int h[OPB], s[OPB], ofs[OPB + 1], lcur[OPB];
  __shared__ unsigned short sortedM[SMCAP];   // 16 KB
  const int tid = threadIdx.x;
  const int b = blockIdx.x;
  const int opLo = b << OPB_SHIFT;
  const int opHi = min(opLo + OPB, N_OP);
  const int nOps = opHi - opLo;
  const int e0 = S[opLo];
  const int n = min(S[opHi] - e0, SMCAP);

  if (tid < OPB) { h[tid] = 0; lcur[tid] = 0; }
  __syncthreads();
  // histogram over ops in bucket
  for (int i = tid; i < n; i += 1024)
    atomicAdd(&h[(int)(bktArr[e0 + i] >> 11) - opLo], 1);
  __syncthreads();
  // exclusive scan of h -> ofs
  if (tid < OPB) s[tid] = h[tid];
  __syncthreads();
  for (int d = 1; d < OPB; d <<= 1) {
    int x = 0, y = 0;
    if (tid < OPB) { x = s[tid]; y = (tid >= d) ? s[tid - d] : 0; }
    __syncthreads();
    if (tid < OPB) s[tid] = x + y;
    __syncthreads();
  }
  if (tid < OPB) ofs[tid] = s[tid] - h[tid];
  __syncthreads();
  // place m values sorted by op
  for (int i = tid; i < n; i += 1024) {
    const unsigned pk = bktArr[e0 + i];
    const int r = (int)(pk >> 11) - opLo;
    const int p = ofs[r] + atomicAdd(&lcur[r], 1);
    sortedM[p] = (unsigned short)(pk & 2047u);
  }
  __syncthreads();

  // compute: wave w handles ops r = w*16 .. w*16+15
  const int wave = tid >> 6;
  const int lane = tid & 63;
  for (int q = 0; q < 16; ++q) {
    const int r = wave * 16 + q;
    if (r >= nOps) break;
    const int i = opLo + r;
    const ushort2 hs = *reinterpret_cast<const ushort2*>(HopProjH + (size_t)i * OUT_DIM + lane * 2);
    float2 acc = make_float2(bf2f(hs.x), bf2f(hs.y));

    // seq aggregation (global CSR)
    const int s0 = S[OFF_SEQ2 + i] - E_OP2M_N;
    const int s1 = S[OFF_SEQ2 + i + 1] - E_OP2M_N;
    float2 a = make_float2(0.f, 0.f);
    for (int e = s0; e < s1; ++e) {
      const int src = seqL[e];
      const ushort2 hh = *reinterpret_cast<const ushort2*>(HopProjH + (size_t)src * OUT_DIM + lane * 2);
      a.x += bf2f(hh.x); a.y += bf2f(hh.y);
    }
    const float wS = 1.0f / (float)max(s1 - s0, 1);
    acc.x += a.x * wS; acc.y += a.y * wS;

    // machine aggregation from LDS-sorted m list
    const int k0 = ofs[r];
    const int k1 = k0 + h[r];
    float2 bb = make_float2(0.f, 0.f);
    int k = k0;
    for (; k + 4 <= k1; k += 4) {
      const int m0 = sortedM[k];
      const int m1 = sortedM[k + 1];
      const int m2 = sortedM[k + 2];
      const int m3 = sortedM[k + 3];
      const ushort2 h0 = *reinterpret_cast<const ushort2*>(HmProjH + (size_t)m0 * OUT_DIM + lane * 2);
      const ushort2 h1 = *reinterpret_cast<const ushort2*>(HmProjH + (size_t)m1 * OUT_DIM + lane * 2);
      const ushort2 h2 = *reinterpret_cast<const ushort2*>(HmProjH + (size_t)m2 * OUT_DIM + lane * 2);
      const ushort2 h3 = *reinterpret_cast<const ushort2*>(HmProjH + (size_t)m3 * OUT_DIM + lane * 2);
      bb.x += (bf2f(h0.x) + bf2f(h1.x)) + (bf2f(h2.x) + bf2f(h3.x));
      bb.y += (bf2f(h0.y) + bf2f(h1.y)) + (bf2f(h2.y) + bf2f(h3.y));
    }
    for (; k < k1; ++k) {
      const int m0 = sortedM[k];
      const ushort2 h0 = *reinterpret_cast<const ushort2*>(HmProjH + (size_t)m0 * OUT_DIM + lane * 2);
      bb.x += bf2f(h0.x); bb.y += bf2f(h0.y);
    }
    const float wO = 1.0f / (float)max(k1 - k0, 1);
    acc.x = fmaxf(acc.x + bb.x * wO, 0.f);
    acc.y = fmaxf(acc.y + bb.y * wO, 0.f);
    *reinterpret_cast<float2*>(out + (size_t)i * OUT_DIM + lane * 2) = acc;
  }
}

// ---------------- machine output: bf16 gather (256 B/row), fp32 accumulate ----------------
__global__ __launch_bounds__(512) void m_out_kernel(
    const unsigned short* __restrict__ HopProjH, const float* __restrict__ HmProj,
    const int* __restrict__ mL, const int* __restrict__ baseM, const int* __restrict__ degM,
    float* __restrict__ outM) {
  __shared__ float red[16][129];    // 129 pad: conflict-free column reads in reduce
  const int m = blockIdx.x;
  const int s0 = baseM[m];
  const int deg = degM[m];
  const int c4   = (threadIdx.x & 31) << 2;   // column base 0..124
  const int slot = threadIdx.x >> 5;          // 0..15
  float ax = 0.f, ay = 0.f, az = 0.f, aw = 0.f;
  int e = slot;
  for (; e + 48 < deg; e += 64) {
    const int o0 = mL[s0 + e];
    const int o1 = mL[s0 + e + 16];
    const int o2 = mL[s0 + e + 32];
    const int o3 = mL[s0 + e + 48];
    const ushort4 h0 = *reinterpret_cast<const ushort4*>(HopProjH + (size_t)o0 * OUT_DIM + c4);
    const ushort4 h1 = *reinterpret_cast<const ushort4*>(HopProjH + (size_t)o1 * OUT_DIM + c4);
    const ushort4 h2 = *reinterpret_cast<const ushort4*>(HopProjH + (size_t)o2 * OUT_DIM + c4);
    const ushort4 h3 = *reinterpret_cast<const ushort4*>(HopProjH + (size_t)o3 * OUT_DIM + c4);
    ax += (bf2f(h0.x) + bf2f(h1.x)) + (bf2f(h2.x) + bf2f(h3.x));
    ay += (bf2f(h0.y) + bf2f(h1.y)) + (bf2f(h2.y) + bf2f(h3.y));
    az += (bf2f(h0.z) + bf2f(h1.z)) + (bf2f(h2.z) + bf2f(h3.z));
    aw += (bf2f(h0.w) + bf2f(h1.w)) + (bf2f(h2.w) + bf2f(h3.w));
  }
  for (; e < deg; e += 16) {
    const int o = mL[s0 + e];
    const ushort4 h = *reinterpret_cast<const ushort4*>(HopProjH + (size_t)o * OUT_DIM + c4);
    ax += bf2f(h.x); ay += bf2f(h.y); az += bf2f(h.z); aw += bf2f(h.w);
  }
  red[slot][c4 + 0] = ax;
  red[slot][c4 + 1] = ay;
  red[slot][c4 + 2] = az;
  red[slot][c4 + 3] = aw;
  __syncthreads();
  if (threadIdx.x < 128) {
    const int col = threadIdx.x;
    float s = 0.f;
    #pragma unroll
    for (int k = 0; k < 16; ++k) s += red[k][col];
    const float v = HmProj[m * OUT_DIM + col] + s / (float)max(deg, 1);
    outM[m * OUT_DIM + col] = fmaxf(v, 0.f);
  }
}

extern "C" void kernel_launch(void* const* d_in, const int* in_sizes, int n_in,
                              void* d_out, int out_size, void* d_ws, size_t ws_size,
                              hipStream_t stream) {
  const float* H_op   = (const float*)d_in[0];
  const float* H_m    = (const float*)d_in[1];
  const int*   E_seq  = (const int*)d_in[2];
  const int*   E_op2m = (const int*)d_in[3];
  const float* W_op   = (const float*)d_in[4];
  const float* b_op   = (const float*)d_in[5];
  const float* W_m    = (const float*)d_in[6];
  const float* b_m    = (const float*)d_in[7];
  float* out = (float*)d_out;

  // ---- workspace layout (element offsets, 4B units unless noted) ----
  float* HmProj  = (float*)d_ws;                                //    256,000
  // zeroed region (contiguous): degOp|degSeq|curSeq|degM|curM|bktCur
  int*   degOp   = (int*)(HmProj + (size_t)N_M * OUT_DIM);      //    100,000
  int*   degSeq  = degOp + N_OP;                                //    100,000
  int*   curSeq  = degSeq + N_OP;                               //    100,000
  int*   degM    = curSeq + N_OP;                               //      2,048
  int*   curM    = degM + 2048;                                 //      2,048
  int*   bktCur  = curM + 2048;                                 //        512
  // end zeroed region (304,608 ints)
  int*   baseM   = bktCur + 512;                                //      2,048
  int*   S       = baseM + 2048;                                //    200,704
  int*   bsums   = S + 200704;                                  //        512
  unsigned* bktArr = (unsigned*)(bsums + 512);                  //  2,000,000
  int*   mL      = (int*)(bktArr + E_OP2M_N);                   //  2,000,000
  int*   seqL    = mL + E_OP2M_N;                               //    100,000
  unsigned short* HopProjH = (unsigned short*)(seqL + E_SEQ_N); // 12,800,000 ushort
  unsigned short* HmProjH  = HopProjH + (size_t)N_OP * OUT_DIM; //    256,000 ushort

  // 1. projections (ops: bf16 only; machines: fp32 + bf16)
  proj_kernel<<<(N_OP + 15) / 16, 256, 0, stream>>>(H_op, W_op, b_op, nullptr, HopProjH, N_OP);
  proj_kernel<<<(N_M + 15) / 16, 256, 0, stream>>>(H_m, W_m, b_m, HmProj, HmProjH, N_M);

  // 2. zero deg/cursor region (one contiguous memset)
  hipMemsetAsync(degOp, 0, (size_t)(3 * N_OP + 2048 + 2048 + 512) * sizeof(int), stream);

  // 3. degrees
  hist_kernel<<<256, 512, 0, stream>>>(E_seq, E_op2m, degOp, degSeq, degM);

  // 4. scans: baseM and S
  scanM_kernel<<<1, 256, 0, stream>>>(degM, baseM);
  const int nScanBlocks = (SCAN_N2 + 1023) / 1024;   // 196
  scanA_kernel<<<nScanBlocks, 256, 0, stream>>>(degOp, S, bsums, SCAN_N2);
  scanB_kernel<<<1, 256, 0, stream>>>(bsums, nScanBlocks);
  scanC_kernel<<<nScanBlocks, 256, 0, stream>>>(S, bsums, SCAN_N2);

  // 5. locality-aware fills
  fill_bkt_kernel<<<BKT_BLOCKS, 512, 0, stream>>>(E_op2m, S, bktCur, bktArr);
  fill_m_kernel<<<FM_BLOCKS, 1024, 0, stream>>>(E_seq, E_op2m, S, baseM,
                                                curM, curSeq, mL, seqL);

  // 6. outputs
  op_out_b_kernel<<<NBKT, 1024, 0, stream>>>(bktArr, HopProjH, HmProjH, S, seqL, out);
  m_out_kernel<<<N_M, 512, 0, stream>>>(HopProjH, HmProj, mL, baseM, degM,
                                        out + (size_t)N_OP * OUT_DIM);
}

// Round 11
// 267.510 us; speedup vs baseline: 3.0080x; 1.4701x over previous
//
#include <hip/hip_runtime.h>

// Problem constants (match reference)
constexpr int N_OP    = 100000;
constexpr int N_M     = 2000;
constexpr int IN_DIM  = 64;
constexpr int OUT_DIM = 128;
constexpr int E_SEQ_N  = 100000;
constexpr int E_OP2M_N = 2000000;

// op-range bucketing: bucket = op >> 8 (256 ops per bucket)
constexpr int OPB_SHIFT = 8;
constexpr int OPB       = 256;
constexpr int NBKT      = (N_OP + OPB - 1) / OPB;   // 391
constexpr int BKT_BLOCKS = 256;
constexpr int BKT_CHUNK  = (E_OP2M_N + BKT_BLOCKS - 1) / BKT_BLOCKS;  // 7813
constexpr int FM_BLOCKS  = 128;
constexpr int FM_CHUNK   = (E_OP2M_N + FM_BLOCKS - 1) / FM_BLOCKS;    // 15625
constexpr int SMCAP      = 8192;   // per-bucket LDS edge capacity (mean 5120, sigma ~72)

// seq scan: degSeq(100000) + trailing zero
constexpr int SCAN_SEQ = N_OP + 1;

__device__ __forceinline__ float bf2f(unsigned short h) {
  return __uint_as_float((unsigned)h << 16);
}
__device__ __forceinline__ unsigned short f2bf(float x) {
  unsigned u = __float_as_uint(x);
  u += 0x7fffu + ((u >> 16) & 1u);      // RNE
  return (unsigned short)(u >> 16);
}

// ---------------- Projection: Y[nrows,128] = X[nrows,64] @ W[64,128] + b ----------------
// 64 rows/block; thread tile = 8 rows x 4 cols; W via ds_read_b128, X via broadcast b128.
__global__ __launch_bounds__(256) void proj_kernel(
    const float* __restrict__ X, const float* __restrict__ W,
    const float* __restrict__ b, float* __restrict__ Y,
    unsigned short* __restrict__ Yh, int nrows) {
  __shared__ float4 Ws4[IN_DIM * 32];   // 64 x 32 quads = 32 KB
  __shared__ float4 Xs4[64 * 16];       // 64 rows x 16 quads = 16 KB
  __shared__ float4 Bs4[32];
  const int t = threadIdx.x;
  const float4* W4 = reinterpret_cast<const float4*>(W);
  #pragma unroll
  for (int k = 0; k < 8; ++k) Ws4[t + k * 256] = W4[t + k * 256];
  if (t < 32) Bs4[t] = reinterpret_cast<const float4*>(b)[t];
  const int row0 = blockIdx.x * 64;
  const float4* X4 = reinterpret_cast<const float4*>(X);
  const int maxQ = nrows * 16;
  #pragma unroll
  for (int k = 0; k < 4; ++k) {
    const int i = t + k * 256;
    const int gi = row0 * 16 + i;
    Xs4[i] = (gi < maxQ) ? X4[gi] : make_float4(0.f, 0.f, 0.f, 0.f);
  }
  __syncthreads();

  const int q = t & 31;     // column quad (cols q*4..q*4+3)
  const int s = t >> 5;     // row slot (rows s*8..s*8+7)
  const float4 bias = Bs4[q];
  float4 acc[8];
  #pragma unroll
  for (int rr = 0; rr < 8; ++rr) acc[rr] = bias;

  for (int j4 = 0; j4 < 16; ++j4) {
    float4 xv[8];
    #pragma unroll
    for (int rr = 0; rr < 8; ++rr) xv[rr] = Xs4[(s * 8 + rr) * 16 + j4];
    #pragma unroll
    for (int jj = 0; jj < 4; ++jj) {
      const float4 w4 = Ws4[(j4 * 4 + jj) * 32 + q];
      #pragma unroll
      for (int rr = 0; rr < 8; ++rr) {
        const float xj = (jj == 0) ? xv[rr].x : (jj == 1) ? xv[rr].y
                       : (jj == 2) ? xv[rr].z : xv[rr].w;
        acc[rr].x = fmaf(xj, w4.x, acc[rr].x);
        acc[rr].y = fmaf(xj, w4.y, acc[rr].y);
        acc[rr].z = fmaf(xj, w4.z, acc[rr].z);
        acc[rr].w = fmaf(xj, w4.w, acc[rr].w);
      }
    }
  }

  #pragma unroll
  for (int rr = 0; rr < 8; ++rr) {
    const int row = row0 + s * 8 + rr;
    if (row >= nrows) break;
    if (Y) *reinterpret_cast<float4*>(Y + (size_t)row * OUT_DIM + q * 4) = acc[rr];
    ushort4 hh;
    hh.x = f2bf(acc[rr].x); hh.y = f2bf(acc[rr].y);
    hh.z = f2bf(acc[rr].z); hh.w = f2bf(acc[rr].w);
    *reinterpret_cast<ushort4*>(Yh + (size_t)row * OUT_DIM + q * 4) = hh;
  }
}

// ---------------- degrees: bucket + machine hists in LDS; seq via global atomics ----------------
__global__ __launch_bounds__(512) void hist2_kernel(
    const int* __restrict__ Eseq, const int* __restrict__ Eop2m,
    int* __restrict__ degSeq, int* __restrict__ degM, int* __restrict__ bktCnt) {
  __shared__ int hm[N_M];    // 8 KB
  __shared__ int hb[NBKT];   // 1.6 KB
  for (int i = threadIdx.x; i < N_M; i += 512) hm[i] = 0;
  for (int i = threadIdx.x; i < NBKT; i += 512) hb[i] = 0;
  __syncthreads();
  const int stride = gridDim.x * 512;
  const int i0 = blockIdx.x * 512 + threadIdx.x;
  for (int e = i0; e < E_OP2M_N; e += stride) {
    atomicAdd(&hb[Eop2m[e] >> OPB_SHIFT], 1);
    atomicAdd(&hm[Eop2m[E_OP2M_N + e]], 1);
  }
  for (int e = i0; e < E_SEQ_N; e += stride)
    atomicAdd(&degSeq[Eseq[E_SEQ_N + e]], 1);
  __syncthreads();
  for (int i = threadIdx.x; i < N_M; i += 512) if (hm[i]) atomicAdd(&degM[i], hm[i]);
  for (int i = threadIdx.x; i < NBKT; i += 512) if (hb[i]) atomicAdd(&bktCnt[i], hb[i]);
}

// ---------------- small scans: block 0 -> baseM (2000); block 1 -> bktBase (391 + total) ----------------
__global__ __launch_bounds__(256) void scan2_kernel(
    const int* __restrict__ degM, int* __restrict__ baseM,
    const int* __restrict__ bktCnt, int* __restrict__ bktBase) {
  __shared__ int s[256];
  const int t = threadIdx.x;
  if (blockIdx.x == 0) {
    int v[8];
    int sum = 0;
    #pragma unroll
    for (int k = 0; k < 8; ++k) {
      const int i = t * 8 + k;
      v[k] = (i < N_M) ? degM[i] : 0;
      sum += v[k];
    }
    s[t] = sum;
    __syncthreads();
    for (int d = 1; d < 256; d <<= 1) {
      const int x = s[t];
      const int y = (t >= d) ? s[t - d] : 0;
      __syncthreads();
      s[t] = x + y;
      __syncthreads();
    }
    int run = s[t] - sum;
    #pragma unroll
    for (int k = 0; k < 8; ++k) {
      const int i = t * 8 + k;
      if (i < N_M) baseM[i] = run;
      run += v[k];
    }
  } else {
    const int v0 = (t * 2     < NBKT) ? bktCnt[t * 2]     : 0;
    const int v1 = (t * 2 + 1 < NBKT) ? bktCnt[t * 2 + 1] : 0;
    const int sum = v0 + v1;
    s[t] = sum;
    __syncthreads();
    for (int d = 1; d < 256; d <<= 1) {
      const int x = s[t];
      const int y = (t >= d) ? s[t - d] : 0;
      __syncthreads();
      s[t] = x + y;
      __syncthreads();
    }
    const int run = s[t] - sum;
    if (t * 2 < NBKT)     bktBase[t * 2]     = run;
    if (t * 2 + 1 < NBKT) bktBase[t * 2 + 1] = run + v0;
    if (t == 255) bktBase[NBKT] = s[255];
  }
}

// ---------------- Hierarchical exclusive scan over degSeq -> S ----------------
__global__ __launch_bounds__(256) void scanA_kernel(
    const int* __restrict__ in, int* __restrict__ out, int* __restrict__ blockSums, int n) {
  __shared__ int s[256];
  const int base = blockIdx.x * 1024 + threadIdx.x * 4;
  int v[4];
  #pragma unroll
  for (int k = 0; k < 4; ++k) v[k] = (base + k < n) ? in[base + k] : 0;
  const int tsum = v[0] + v[1] + v[2] + v[3];
  s[threadIdx.x] = tsum;
  __syncthreads();
  for (int d = 1; d < 256; d <<= 1) {
    const int x = s[threadIdx.x];
    const int y = (threadIdx.x >= d) ? s[threadIdx.x - d] : 0;
    __syncthreads();
    s[threadIdx.x] = x + y;
    __syncthreads();
  }
  int run = s[threadIdx.x] - tsum;
  if (threadIdx.x == 255) blockSums[blockIdx.x] = s[255];
  #pragma unroll
  for (int k = 0; k < 4; ++k) {
    if (base + k < n) out[base + k] = run;
    run += v[k];
  }
}

__global__ __launch_bounds__(256) void scanB_kernel(int* __restrict__ bs, int nb) {
  __shared__ int s[256];
  const int t = threadIdx.x;
  const int v = (t < nb) ? bs[t] : 0;
  s[t] = v;
  __syncthreads();
  for (int d = 1; d < 256; d <<= 1) {
    const int x = s[t];
    const int y = (t >= d) ? s[t - d] : 0;
    __syncthreads();
    s[t] = x + y;
    __syncthreads();
  }
  if (t < nb) bs[t] = s[t] - v;
}

__global__ __launch_bounds__(256) void scanC_kernel(
    int* __restrict__ out, const int* __restrict__ bs, int n) {
  const int base = blockIdx.x * 1024 + threadIdx.x * 4;
  const int add = bs[blockIdx.x];
  #pragma unroll
  for (int k = 0; k < 4; ++k)
    if (base + k < n) out[base + k] += add;
}

// ---------------- bucket fill: pack (op<<11|m) into op-range buckets ----------------
__global__ __launch_bounds__(512) void fill_bkt_kernel(
    const int* __restrict__ Eop2m, const int* __restrict__ bktBase,
    int* __restrict__ bktCur, unsigned* __restrict__ bktArr) {
  __shared__ int h[NBKT], ofs[NBKT], lcur[NBKT];
  for (int i = threadIdx.x; i < NBKT; i += 512) { h[i] = 0; lcur[i] = 0; }
  __syncthreads();
  const int e0 = blockIdx.x * BKT_CHUNK;
  const int e1 = min(E_OP2M_N, e0 + BKT_CHUNK);
  for (int e = e0 + threadIdx.x; e < e1; e += 512)
    atomicAdd(&h[Eop2m[e] >> OPB_SHIFT], 1);
  __syncthreads();
  for (int t = threadIdx.x; t < NBKT; t += 512)
    ofs[t] = atomicAdd(&bktCur[t], h[t]);
  __syncthreads();
  for (int e = e0 + threadIdx.x; e < e1; e += 512) {
    const int op = Eop2m[e];
    const int m  = Eop2m[E_OP2M_N + e];
    const int bb = op >> OPB_SHIFT;
    const int p  = bktBase[bb] + ofs[bb] + atomicAdd(&lcur[bb], 1);
    bktArr[p] = ((unsigned)op << 11) | (unsigned)m;
  }
}

// ---------------- mL fill: hist -> reservation -> scatter (m axis) + seqL tail ----------------
__global__ __launch_bounds__(1024) void fill_m_kernel(
    const int* __restrict__ Eseq, const int* __restrict__ Eop2m,
    const int* __restrict__ S, const int* __restrict__ baseM,
    int* __restrict__ curM, int* __restrict__ curSeq,
    int* __restrict__ mL, int* __restrict__ seqL) {
  __shared__ int h[N_M], ofs[N_M], lcur[N_M];   // 24 KB
  for (int i = threadIdx.x; i < N_M; i += 1024) { h[i] = 0; lcur[i] = 0; }
  __syncthreads();
  const int e0 = blockIdx.x * FM_CHUNK;
  const int e1 = min(E_OP2M_N, e0 + FM_CHUNK);
  for (int e = e0 + threadIdx.x; e < e1; e += 1024)
    atomicAdd(&h[Eop2m[E_OP2M_N + e]], 1);
  __syncthreads();
  for (int t = threadIdx.x; t < N_M; t += 1024)
    ofs[t] = atomicAdd(&curM[t], h[t]);
  __syncthreads();
  for (int e = e0 + threadIdx.x; e < e1; e += 1024) {
    const int op = Eop2m[e];
    const int m  = Eop2m[E_OP2M_N + e];
    mL[baseM[m] + ofs[m] + atomicAdd(&lcur[m], 1)] = op;
  }
  const int stride = gridDim.x * 1024;
  for (int e = blockIdx.x * 1024 + threadIdx.x; e < E_SEQ_N; e += stride) {
    const int src = Eseq[e];
    const int dst = Eseq[E_SEQ_N + e];
    seqL[S[dst] + atomicAdd(&curSeq[dst], 1)] = src;
  }
}

// ---------------- op output: one block per bucket; in-LDS sort by op, then gather ----------------
__global__ __launch_bounds__(1024) void op_out_b_kernel(
    const unsigned* __restrict__ bktArr, const unsigned short* __restrict__ HopProjH,
    const unsigned short* __restrict__ HmProjH, const int* __restrict__ bktBase,
    const int* __restrict__ S, const int* __restrict__ seqL, float* __restrict__ out) {
  __shared__ int h[OPB], s[OPB], ofs[OPB + 1], lcur[OPB];
  __shared__ unsigned short sortedM[SMCAP];   // 16 KB
  const int tid = threadIdx.x;
  const int b = blockIdx.x;
  const int opLo = b << OPB_SHIFT;
  const int opHi = min(opLo + OPB, N_OP);
  const int nOps = opHi - opLo;
  const int e0 = bktBase[b];
  const int n = min(bktBase[b + 1] - e0, SMCAP);

  if (tid < OPB) { h[tid] = 0; lcur[tid] = 0; }
  __syncthreads();
  for (int i = tid; i < n; i += 1024)
    atomicAdd(&h[(int)(bktArr[e0 + i] >> 11) - opLo], 1);
  __syncthreads();
  if (tid < OPB) s[tid] = h[tid];
  __syncthreads();
  for (int d = 1; d < OPB; d <<= 1) {
    int x = 0, y = 0;
    if (tid < OPB) { x = s[tid]; y = (tid >= d) ? s[tid - d] : 0; }
    __syncthreads();
    if (tid < OPB) s[tid] = x + y;
    __syncthreads();
  }
  if (tid < OPB) ofs[tid] = s[tid] - h[tid];
  __syncthreads();
  for (int i = tid; i < n; i += 1024) {
    const unsigned pk = bktArr[e0 + i];
    const int r = (int)(pk >> 11) - opLo;
    const int p = ofs[r] + atomicAdd(&lcur[r], 1);
    sortedM[p] = (unsigned short)(pk & 2047u);
  }
  __syncthreads();

  const int wave = tid >> 6;
  const int lane = tid & 63;
  for (int qq = 0; qq < 16; ++qq) {
    const int r = wave * 16 + qq;
    if (r >= nOps) break;
    const int i = opLo + r;
    const ushort2 hs = *reinterpret_cast<const ushort2*>(HopProjH + (size_t)i * OUT_DIM + lane * 2);
    float2 acc = make_float2(bf2f(hs.x), bf2f(hs.y));

    const int s0 = S[i];
    const int s1 = S[i + 1];
    float2 a = make_float2(0.f, 0.f);
    for (int e = s0; e < s1; ++e) {
      const int src = seqL[e];
      const ushort2 hh = *reinterpret_cast<const ushort2*>(HopProjH + (size_t)src * OUT_DIM + lane * 2);
      a.x += bf2f(hh.x); a.y += bf2f(hh.y);
    }
    const float wS = 1.0f / (float)max(s1 - s0, 1);
    acc.x += a.x * wS; acc.y += a.y * wS;

    const int k0 = ofs[r];
    const int k1 = k0 + h[r];
    float2 bb = make_float2(0.f, 0.f);
    int k = k0;
    for (; k + 4 <= k1; k += 4) {
      const int m0 = sortedM[k];
      const int m1 = sortedM[k + 1];
      const int m2 = sortedM[k + 2];
      const int m3 = sortedM[k + 3];
      const ushort2 h0 = *reinterpret_cast<const ushort2*>(HmProjH + (size_t)m0 * OUT_DIM + lane * 2);
      const ushort2 h1 = *reinterpret_cast<const ushort2*>(HmProjH + (size_t)m1 * OUT_DIM + lane * 2);
      const ushort2 h2 = *reinterpret_cast<const ushort2*>(HmProjH + (size_t)m2 * OUT_DIM + lane * 2);
      const ushort2 h3 = *reinterpret_cast<const ushort2*>(HmProjH + (size_t)m3 * OUT_DIM + lane * 2);
      bb.x += (bf2f(h0.x) + bf2f(h1.x)) + (bf2f(h2.x) + bf2f(h3.x));
      bb.y += (bf2f(h0.y) + bf2f(h1.y)) + (bf2f(h2.y) + bf2f(h3.y));
    }
    for (; k < k1; ++k) {
      const int m0 = sortedM[k];
      const ushort2 h0 = *reinterpret_cast<const ushort2*>(HmProjH + (size_t)m0 * OUT_DIM + lane * 2);
      bb.x += bf2f(h0.x); bb.y += bf2f(h0.y);
    }
    const float wO = 1.0f / (float)max(k1 - k0, 1);
    acc.x = fmaxf(acc.x + bb.x * wO, 0.f);
    acc.y = fmaxf(acc.y + bb.y * wO, 0.f);
    *reinterpret_cast<float2*>(out + (size_t)i * OUT_DIM + lane * 2) = acc;
  }
}

// ---------------- machine output: bf16 gather (256 B/row), fp32 accumulate ----------------
__global__ __launch_bounds__(512) void m_out_kernel(
    const unsigned short* __restrict__ HopProjH, const float* __restrict__ HmProj,
    const int* __restrict__ mL, const int* __restrict__ baseM, const int* __restrict__ degM,
    float* __restrict__ outM) {
  __shared__ float red[16][129];
  const int m = blockIdx.x;
  const int s0 = baseM[m];
  const int deg = degM[m];
  const int c4   = (threadIdx.x & 31) << 2;
  const int slot = threadIdx.x >> 5;
  float ax = 0.f, ay = 0.f, az = 0.f, aw = 0.f;
  int e = slot;
  for (; e + 48 < deg; e += 64) {
    const int o0 = mL[s0 + e];
    const int o1 = mL[s0 + e + 16];
    const int o2 = mL[s0 + e + 32];
    const int o3 = mL[s0 + e + 48];
    const ushort4 h0 = *reinterpret_cast<const ushort4*>(HopProjH + (size_t)o0 * OUT_DIM + c4);
    const ushort4 h1 = *reinterpret_cast<const ushort4*>(HopProjH + (size_t)o1 * OUT_DIM + c4);
    const ushort4 h2 = *reinterpret_cast<const ushort4*>(HopProjH + (size_t)o2 * OUT_DIM + c4);
    const ushort4 h3 = *reinterpret_cast<const ushort4*>(HopProjH + (size_t)o3 * OUT_DIM + c4);
    ax += (bf2f(h0.x) + bf2f(h1.x)) + (bf2f(h2.x) + bf2f(h3.x));
    ay += (bf2f(h0.y) + bf2f(h1.y)) + (bf2f(h2.y) + bf2f(h3.y));
    az += (bf2f(h0.z) + bf2f(h1.z)) + (bf2f(h2.z) + bf2f(h3.z));
    aw += (bf2f(h0.w) + bf2f(h1.w)) + (bf2f(h2.w) + bf2f(h3.w));
  }
  for (; e < deg; e += 16) {
    const int o = mL[s0 + e];
    const ushort4 h = *reinterpret_cast<const ushort4*>(HopProjH + (size_t)o * OUT_DIM + c4);
    ax += bf2f(h.x); ay += bf2f(h.y); az += bf2f(h.z); aw += bf2f(h.w);
  }
  red[slot][c4 + 0] = ax;
  red[slot][c4 + 1] = ay;
  red[slot][c4 + 2] = az;
  red[slot][c4 + 3] = aw;
  __syncthreads();
  if (threadIdx.x < 128) {
    const int col = threadIdx.x;
    float sx = 0.f;
    #pragma unroll
    for (int k = 0; k < 16; ++k) sx += red[k][col];
    const float v = HmProj[m * OUT_DIM + col] + sx / (float)max(deg, 1);
    outM[m * OUT_DIM + col] = fmaxf(v, 0.f);
  }
}

extern "C" void kernel_launch(void* const* d_in, const int* in_sizes, int n_in,
                              void* d_out, int out_size, void* d_ws, size_t ws_size,
                              hipStream_t stream) {
  const float* H_op   = (const float*)d_in[0];
  const float* H_m    = (const float*)d_in[1];
  const int*   E_seq  = (const int*)d_in[2];
  const int*   E_op2m = (const int*)d_in[3];
  const float* W_op   = (const float*)d_in[4];
  const float* b_op   = (const float*)d_in[5];
  const float* W_m    = (const float*)d_in[6];
  const float* b_m    = (const float*)d_in[7];
  float* out = (float*)d_out;

  // ---- workspace layout (element offsets, 4B units unless noted) ----
  float* HmProj  = (float*)d_ws;                                //    256,000
  // zeroed region: degSeq|curSeq|degM|curM|bktCnt|bktCur
  int*   degSeq  = (int*)(HmProj + (size_t)N_M * OUT_DIM);      //    100,000
  int*   curSeq  = degSeq + N_OP;                               //    100,000
  int*   degM    = curSeq + N_OP;                               //      2,048
  int*   curM    = degM + 2048;                                 //      2,048
  int*   bktCnt  = curM + 2048;                                 //        512
  int*   bktCur  = bktCnt + 512;                                //        512
  // end zeroed region (205,120 ints)
  int*   baseM   = bktCur + 512;                                //      2,048
  int*   bktBase = baseM + 2048;                                //        512 (needs 392)
  int*   S       = bktBase + 512;                               //    100,352
  int*   bsums   = S + 100352;                                  //        512
  unsigned* bktArr = (unsigned*)(bsums + 512);                  //  2,000,000
  int*   mL      = (int*)(bktArr + E_OP2M_N);                   //  2,000,000
  int*   seqL    = mL + E_OP2M_N;                               //    100,000
  unsigned short* HopProjH = (unsigned short*)(seqL + E_SEQ_N); // 12,800,000 ushort
  unsigned short* HmProjH  = HopProjH + (size_t)N_OP * OUT_DIM; //    256,000 ushort

  // 1. projections (ops: bf16 only; machines: fp32 + bf16)
  proj_kernel<<<(N_OP + 63) / 64, 256, 0, stream>>>(H_op, W_op, b_op, nullptr, HopProjH, N_OP);
  proj_kernel<<<(N_M + 63) / 64, 256, 0, stream>>>(H_m, W_m, b_m, HmProj, HmProjH, N_M);

  // 2. zero deg/cursor region (one contiguous memset)
  hipMemsetAsync(degSeq, 0, (size_t)(2 * N_OP + 2048 + 2048 + 512 + 512) * sizeof(int), stream);

  // 3. histograms (no per-op global atomics)
  hist2_kernel<<<256, 512, 0, stream>>>(E_seq, E_op2m, degSeq, degM, bktCnt);

  // 4. scans: baseM + bktBase (small), S over degSeq
  scan2_kernel<<<2, 256, 0, stream>>>(degM, baseM, bktCnt, bktBase);
  const int nScanBlocks = (SCAN_SEQ + 1023) / 1024;   // 98
  scanA_kernel<<<nScanBlocks, 256, 0, stream>>>(degSeq, S, bsums, SCAN_SEQ);
  scanB_kernel<<<1, 256, 0, stream>>>(bsums, nScanBlocks);
  scanC_kernel<<<nScanBlocks, 256, 0, stream>>>(S, bsums, SCAN_SEQ);

  // 5. locality-aware fills
  fill_bkt_kernel<<<BKT_BLOCKS, 512, 0, stream>>>(E_op2m, bktBase, bktCur, bktArr);
  fill_m_kernel<<<FM_BLOCKS, 1024, 0, stream>>>(E_seq, E_op2m, S, baseM,
                                                curM, curSeq, mL, seqL);

  // 6. outputs
  op_out_b_kernel<<<NBKT, 1024, 0, stream>>>(bktArr, HopProjH, HmProjH, bktBase, S, seqL, out);
  m_out_kernel<<<N_M, 512, 0, stream>>>(HopProjH, HmProj, mL, baseM, degM,
                                        out + (size_t)N_OP * OUT_DIM);
}

// Round 12
// 260.758 us; speedup vs baseline: 3.0859x; 1.0259x over previous
//
#include <hip/hip_runtime.h>

// Problem constants (match reference)
constexpr int N_OP    = 100000;
constexpr int N_M     = 2000;
constexpr int IN_DIM  = 64;
constexpr int OUT_DIM = 128;
constexpr int E_SEQ_N  = 100000;
constexpr int E_OP2M_N = 2000000;

// op-range bucketing: bucket = op >> 7 (128 ops per bucket)
constexpr int OPB_SHIFT = 7;
constexpr int OPB       = 128;
constexpr int NBKT      = (N_OP + OPB - 1) / OPB;   // 782
constexpr int FILL_BLOCKS = 256;
constexpr int FILL_CHUNK  = (E_OP2M_N + FILL_BLOCKS - 1) / FILL_BLOCKS;  // 7813
constexpr int SMCAP      = 4096;   // per-bucket LDS edge capacity (mean 2560, +30 sigma)

// seq scan: degSeq(100000) + trailing zero
constexpr int SCAN_SEQ = N_OP + 1;

__device__ __forceinline__ float bf2f(unsigned short h) {
  return __uint_as_float((unsigned)h << 16);
}
__device__ __forceinline__ unsigned short f2bf(float x) {
  unsigned u = __float_as_uint(x);
  u += 0x7fffu + ((u >> 16) & 1u);      // RNE
  return (unsigned short)(u >> 16);
}

// ---------------- Projection: Y[nrows,128] = X[nrows,64] @ W[64,128] + b ----------------
// 64 rows/block; thread tile = 8 rows x 4 cols; W via ds_read_b128, X via broadcast b128.
__global__ __launch_bounds__(256) void proj_kernel(
    const float* __restrict__ X, const float* __restrict__ W,
    const float* __restrict__ b, float* __restrict__ Y,
    unsigned short* __restrict__ Yh, int nrows) {
  __shared__ float4 Ws4[IN_DIM * 32];   // 32 KB
  __shared__ float4 Xs4[64 * 16];       // 16 KB
  __shared__ float4 Bs4[32];
  const int t = threadIdx.x;
  const float4* W4 = reinterpret_cast<const float4*>(W);
  #pragma unroll
  for (int k = 0; k < 8; ++k) Ws4[t + k * 256] = W4[t + k * 256];
  if (t < 32) Bs4[t] = reinterpret_cast<const float4*>(b)[t];
  const int row0 = blockIdx.x * 64;
  const float4* X4 = reinterpret_cast<const float4*>(X);
  const int maxQ = nrows * 16;
  #pragma unroll
  for (int k = 0; k < 4; ++k) {
    const int i = t + k * 256;
    const int gi = row0 * 16 + i;
    Xs4[i] = (gi < maxQ) ? X4[gi] : make_float4(0.f, 0.f, 0.f, 0.f);
  }
  __syncthreads();

  const int q = t & 31;     // column quad
  const int s = t >> 5;     // row slot
  const float4 bias = Bs4[q];
  float4 acc[8];
  #pragma unroll
  for (int rr = 0; rr < 8; ++rr) acc[rr] = bias;

  for (int j4 = 0; j4 < 16; ++j4) {
    float4 xv[8];
    #pragma unroll
    for (int rr = 0; rr < 8; ++rr) xv[rr] = Xs4[(s * 8 + rr) * 16 + j4];
    #pragma unroll
    for (int jj = 0; jj < 4; ++jj) {
      const float4 w4 = Ws4[(j4 * 4 + jj) * 32 + q];
      #pragma unroll
      for (int rr = 0; rr < 8; ++rr) {
        const float xj = (jj == 0) ? xv[rr].x : (jj == 1) ? xv[rr].y
                       : (jj == 2) ? xv[rr].z : xv[rr].w;
        acc[rr].x = fmaf(xj, w4.x, acc[rr].x);
        acc[rr].y = fmaf(xj, w4.y, acc[rr].y);
        acc[rr].z = fmaf(xj, w4.z, acc[rr].z);
        acc[rr].w = fmaf(xj, w4.w, acc[rr].w);
      }
    }
  }

  #pragma unroll
  for (int rr = 0; rr < 8; ++rr) {
    const int row = row0 + s * 8 + rr;
    if (row >= nrows) break;
    if (Y) *reinterpret_cast<float4*>(Y + (size_t)row * OUT_DIM + q * 4) = acc[rr];
    ushort4 hh;
    hh.x = f2bf(acc[rr].x); hh.y = f2bf(acc[rr].y);
    hh.z = f2bf(acc[rr].z); hh.w = f2bf(acc[rr].w);
    *reinterpret_cast<ushort4*>(Yh + (size_t)row * OUT_DIM + q * 4) = hh;
  }
}

// ---------------- degrees: bucket + machine hists in LDS; seq via global atomics ----------------
__global__ __launch_bounds__(512) void hist2_kernel(
    const int* __restrict__ Eseq, const int* __restrict__ Eop2m,
    int* __restrict__ degSeq, int* __restrict__ degM, int* __restrict__ bktCnt) {
  __shared__ int hm[N_M];    // 8 KB
  __shared__ int hb[NBKT];   // 3.1 KB
  for (int i = threadIdx.x; i < N_M; i += 512) hm[i] = 0;
  for (int i = threadIdx.x; i < NBKT; i += 512) hb[i] = 0;
  __syncthreads();
  const int stride = gridDim.x * 512;
  const int i0 = blockIdx.x * 512 + threadIdx.x;
  for (int e = i0; e < E_OP2M_N; e += stride) {
    atomicAdd(&hb[Eop2m[e] >> OPB_SHIFT], 1);
    atomicAdd(&hm[Eop2m[E_OP2M_N + e]], 1);
  }
  for (int e = i0; e < E_SEQ_N; e += stride)
    atomicAdd(&degSeq[Eseq[E_SEQ_N + e]], 1);
  __syncthreads();
  for (int i = threadIdx.x; i < N_M; i += 512) if (hm[i]) atomicAdd(&degM[i], hm[i]);
  for (int i = threadIdx.x; i < NBKT; i += 512) if (hb[i]) atomicAdd(&bktCnt[i], hb[i]);
}

// ---------------- small scans: block 0 -> baseM (2000); block 1 -> bktBase (782 + total) ----------------
__global__ __launch_bounds__(256) void scan2_kernel(
    const int* __restrict__ degM, int* __restrict__ baseM,
    const int* __restrict__ bktCnt, int* __restrict__ bktBase) {
  __shared__ int s[256];
  const int t = threadIdx.x;
  if (blockIdx.x == 0) {
    int v[8];
    int sum = 0;
    #pragma unroll
    for (int k = 0; k < 8; ++k) {
      const int i = t * 8 + k;
      v[k] = (i < N_M) ? degM[i] : 0;
      sum += v[k];
    }
    s[t] = sum;
    __syncthreads();
    for (int d = 1; d < 256; d <<= 1) {
      const int x = s[t];
      const int y = (t >= d) ? s[t - d] : 0;
      __syncthreads();
      s[t] = x + y;
      __syncthreads();
    }
    int run = s[t] - sum;
    #pragma unroll
    for (int k = 0; k < 8; ++k) {
      const int i = t * 8 + k;
      if (i < N_M) baseM[i] = run;
      run += v[k];
    }
  } else {
    int v[4];
    int sum = 0;
    #pragma unroll
    for (int k = 0; k < 4; ++k) {
      const int i = t * 4 + k;
      v[k] = (i < NBKT) ? bktCnt[i] : 0;
      sum += v[k];
    }
    s[t] = sum;
    __syncthreads();
    for (int d = 1; d < 256; d <<= 1) {
      const int x = s[t];
      const int y = (t >= d) ? s[t - d] : 0;
      __syncthreads();
      s[t] = x + y;
      __syncthreads();
    }
    int run = s[t] - sum;
    #pragma unroll
    for (int k = 0; k < 4; ++k) {
      const int i = t * 4 + k;
      if (i <= NBKT) bktBase[i] = run;   // also writes bktBase[NBKT] when i==NBKT... handled below
      run += v[k];
    }
    if (t == 255) bktBase[NBKT] = s[255];
  }
}

// ---------------- Hierarchical exclusive scan over degSeq -> S ----------------
__global__ __launch_bounds__(256) void scanA_kernel(
    const int* __restrict__ in, int* __restrict__ out, int* __restrict__ blockSums, int n) {
  __shared__ int s[256];
  const int base = blockIdx.x * 1024 + threadIdx.x * 4;
  int v[4];
  #pragma unroll
  for (int k = 0; k < 4; ++k) v[k] = (base + k < n) ? in[base + k] : 0;
  const int tsum = v[0] + v[1] + v[2] + v[3];
  s[threadIdx.x] = tsum;
  __syncthreads();
  for (int d = 1; d < 256; d <<= 1) {
    const int x = s[threadIdx.x];
    const int y = (threadIdx.x >= d) ? s[threadIdx.x - d] : 0;
    __syncthreads();
    s[threadIdx.x] = x + y;
    __syncthreads();
  }
  int run = s[threadIdx.x] - tsum;
  if (threadIdx.x == 255) blockSums[blockIdx.x] = s[255];
  #pragma unroll
  for (int k = 0; k < 4; ++k) {
    if (base + k < n) out[base + k] = run;
    run += v[k];
  }
}

__global__ __launch_bounds__(256) void scanB_kernel(int* __restrict__ bs, int nb) {
  __shared__ int s[256];
  const int t = threadIdx.x;
  const int v = (t < nb) ? bs[t] : 0;
  s[t] = v;
  __syncthreads();
  for (int d = 1; d < 256; d <<= 1) {
    const int x = s[t];
    const int y = (t >= d) ? s[t - d] : 0;
    __syncthreads();
    s[t] = x + y;
    __syncthreads();
  }
  if (t < nb) bs[t] = s[t] - v;
}

__global__ __launch_bounds__(256) void scanC_kernel(
    int* __restrict__ out, const int* __restrict__ bs, int n) {
  const int base = blockIdx.x * 1024 + threadIdx.x * 4;
  const int add = bs[blockIdx.x];
  #pragma unroll
  for (int k = 0; k < 4; ++k)
    if (base + k < n) out[base + k] += add;
}

// ---------------- fused fill: bktArr (op-major packed) + mL (m-major) + seqL ----------------
__global__ __launch_bounds__(512) void fill_fused_kernel(
    const int* __restrict__ Eseq, const int* __restrict__ Eop2m,
    const int* __restrict__ bktBase, const int* __restrict__ baseM, const int* __restrict__ S,
    int* __restrict__ bktCur, int* __restrict__ curM, int* __restrict__ curSeq,
    unsigned* __restrict__ bktArr, int* __restrict__ mL, int* __restrict__ seqL) {
  __shared__ int hb[NBKT], ofsB[NBKT], lcurB[NBKT];   // 9.4 KB
  __shared__ int hm[N_M], ofsM[N_M], lcurM[N_M];      // 24 KB
  for (int i = threadIdx.x; i < NBKT; i += 512) { hb[i] = 0; lcurB[i] = 0; }
  for (int i = threadIdx.x; i < N_M; i += 512)  { hm[i] = 0; lcurM[i] = 0; }
  __syncthreads();
  const int e0 = blockIdx.x * FILL_CHUNK;
  const int e1 = min(E_OP2M_N, e0 + FILL_CHUNK);
  for (int e = e0 + threadIdx.x; e < e1; e += 512) {
    atomicAdd(&hb[Eop2m[e] >> OPB_SHIFT], 1);
    atomicAdd(&hm[Eop2m[E_OP2M_N + e]], 1);
  }
  __syncthreads();
  for (int t = threadIdx.x; t < NBKT; t += 512) ofsB[t] = atomicAdd(&bktCur[t], hb[t]);
  for (int t = threadIdx.x; t < N_M; t += 512)  ofsM[t] = atomicAdd(&curM[t], hm[t]);
  __syncthreads();
  for (int e = e0 + threadIdx.x; e < e1; e += 512) {
    const int op = Eop2m[e];
    const int m  = Eop2m[E_OP2M_N + e];
    const int bb = op >> OPB_SHIFT;
    bktArr[bktBase[bb] + ofsB[bb] + atomicAdd(&lcurB[bb], 1)] = ((unsigned)op << 11) | (unsigned)m;
    mL[baseM[m] + ofsM[m] + atomicAdd(&lcurM[m], 1)] = op;
  }
  // seqL cursor scatter (small: 100K edges)
  const int stride = gridDim.x * 512;
  for (int e = blockIdx.x * 512 + threadIdx.x; e < E_SEQ_N; e += stride) {
    const int src = Eseq[e];
    const int dst = Eseq[E_SEQ_N + e];
    seqL[S[dst] + atomicAdd(&curSeq[dst], 1)] = src;
  }
}

// ---------------- op output: one block (512 thr) per 128-op bucket ----------------
__global__ __launch_bounds__(512) void op_out_b_kernel(
    const unsigned* __restrict__ bktArr, const unsigned short* __restrict__ HopProjH,
    const unsigned short* __restrict__ HmProjH, const int* __restrict__ bktBase,
    const int* __restrict__ S, const int* __restrict__ seqL, float* __restrict__ out) {
  __shared__ int h[OPB], s[OPB], ofs[OPB], lcur[OPB];
  __shared__ unsigned short sortedM[SMCAP];   // 8 KB
  const int tid = threadIdx.x;
  const int b = blockIdx.x;
  const int opLo = b << OPB_SHIFT;
  const int opHi = min(opLo + OPB, N_OP);
  const int nOps = opHi - opLo;
  const int e0 = bktBase[b];
  const int n = min(bktBase[b + 1] - e0, SMCAP);

  if (tid < OPB) { h[tid] = 0; lcur[tid] = 0; }
  __syncthreads();
  for (int i = tid; i < n; i += 512)
    atomicAdd(&h[(int)(bktArr[e0 + i] >> 11) - opLo], 1);
  __syncthreads();
  if (tid < OPB) s[tid] = h[tid];
  __syncthreads();
  for (int d = 1; d < OPB; d <<= 1) {
    int x = 0, y = 0;
    if (tid < OPB) { x = s[tid]; y = (tid >= d) ? s[tid - d] : 0; }
    __syncthreads();
    if (tid < OPB) s[tid] = x + y;
    __syncthreads();
  }
  if (tid < OPB) ofs[tid] = s[tid] - h[tid];
  __syncthreads();
  for (int i = tid; i < n; i += 512) {
    const unsigned pk = bktArr[e0 + i];
    const int r = (int)(pk >> 11) - opLo;
    const int p = ofs[r] + atomicAdd(&lcur[r], 1);
    sortedM[p] = (unsigned short)(pk & 2047u);
  }
  __syncthreads();

  const int wave = tid >> 6;    // 0..7
  const int lane = tid & 63;
  for (int qq = 0; qq < 16; ++qq) {
    const int r = wave * 16 + qq;
    if (r >= nOps) break;
    const int i = opLo + r;
    const ushort2 hs = *reinterpret_cast<const ushort2*>(HopProjH + (size_t)i * OUT_DIM + lane * 2);
    float2 acc = make_float2(bf2f(hs.x), bf2f(hs.y));

    // seq aggregation
    const int s0 = S[i];
    const int s1 = S[i + 1];
    float2 a = make_float2(0.f, 0.f);
    for (int e = s0; e < s1; ++e) {
      const int src = seqL[e];
      const ushort2 hh = *reinterpret_cast<const ushort2*>(HopProjH + (size_t)src * OUT_DIM + lane * 2);
      a.x += bf2f(hh.x); a.y += bf2f(hh.y);
    }
    const float wS = 1.0f / (float)max(s1 - s0, 1);
    acc.x += a.x * wS; acc.y += a.y * wS;

    // machine aggregation, 8-deep ILP
    const int k0 = ofs[r];
    const int k1 = k0 + h[r];
    float2 bb = make_float2(0.f, 0.f);
    int k = k0;
    for (; k + 8 <= k1; k += 8) {
      ushort2 hv[8];
      #pragma unroll
      for (int u = 0; u < 8; ++u) {
        const int mu = sortedM[k + u];
        hv[u] = *reinterpret_cast<const ushort2*>(HmProjH + (size_t)mu * OUT_DIM + lane * 2);
      }
      #pragma unroll
      for (int u = 0; u < 8; ++u) {
        bb.x += bf2f(hv[u].x);
        bb.y += bf2f(hv[u].y);
      }
    }
    for (; k < k1; ++k) {
      const int m0 = sortedM[k];
      const ushort2 h0 = *reinterpret_cast<const ushort2*>(HmProjH + (size_t)m0 * OUT_DIM + lane * 2);
      bb.x += bf2f(h0.x); bb.y += bf2f(h0.y);
    }
    const float wO = 1.0f / (float)max(k1 - k0, 1);
    acc.x = fmaxf(acc.x + bb.x * wO, 0.f);
    acc.y = fmaxf(acc.y + bb.y * wO, 0.f);
    *reinterpret_cast<float2*>(out + (size_t)i * OUT_DIM + lane * 2) = acc;
  }
}

// ---------------- machine output: bf16 gather (256 B/row), fp32 accumulate ----------------
__global__ __launch_bounds__(512) void m_out_kernel(
    const unsigned short* __restrict__ HopProjH, const float* __restrict__ HmProj,
    const int* __restrict__ mL, const int* __restrict__ baseM, const int* __restrict__ degM,
    float* __restrict__ outM) {
  __shared__ float red[16][129];
  const int m = blockIdx.x;
  const int s0 = baseM[m];
  const int deg = degM[m];
  const int c4   = (threadIdx.x & 31) << 2;
  const int slot = threadIdx.x >> 5;
  float ax = 0.f, ay = 0.f, az = 0.f, aw = 0.f;
  int e = slot;
  for (; e + 48 < deg; e += 64) {
    const int o0 = mL[s0 + e];
    const int o1 = mL[s0 + e + 16];
    const int o2 = mL[s0 + e + 32];
    const int o3 = mL[s0 + e + 48];
    const ushort4 h0 = *reinterpret_cast<const ushort4*>(HopProjH + (size_t)o0 * OUT_DIM + c4);
    const ushort4 h1 = *reinterpret_cast<const ushort4*>(HopProjH + (size_t)o1 * OUT_DIM + c4);
    const ushort4 h2 = *reinterpret_cast<const ushort4*>(HopProjH + (size_t)o2 * OUT_DIM + c4);
    const ushort4 h3 = *reinterpret_cast<const ushort4*>(HopProjH + (size_t)o3 * OUT_DIM + c4);
    ax += (bf2f(h0.x) + bf2f(h1.x)) + (bf2f(h2.x) + bf2f(h3.x));
    ay += (bf2f(h0.y) + bf2f(h1.y)) + (bf2f(h2.y) + bf2f(h3.y));
    az += (bf2f(h0.z) + bf2f(h1.z)) + (bf2f(h2.z) + bf2f(h3.z));
    aw += (bf2f(h0.w) + bf2f(h1.w)) + (bf2f(h2.w) + bf2f(h3.w));
  }
  for (; e < deg; e += 16) {
    const int o = mL[s0 + e];
    const ushort4 h = *reinterpret_cast<const ushort4*>(HopProjH + (size_t)o * OUT_DIM + c4);
    ax += bf2f(h.x); ay += bf2f(h.y); az += bf2f(h.z); aw += bf2f(h.w);
  }
  red[slot][c4 + 0] = ax;
  red[slot][c4 + 1] = ay;
  red[slot][c4 + 2] = az;
  red[slot][c4 + 3] = aw;
  __syncthreads();
  if (threadIdx.x < 128) {
    const int col = threadIdx.x;
    float sx = 0.f;
    #pragma unroll
    for (int k = 0; k < 16; ++k) sx += red[k][col];
    const float v = HmProj[m * OUT_DIM + col] + sx / (float)max(deg, 1);
    outM[m * OUT_DIM + col] = fmaxf(v, 0.f);
  }
}

extern "C" void kernel_launch(void* const* d_in, const int* in_sizes, int n_in,
                              void* d_out, int out_size, void* d_ws, size_t ws_size,
                              hipStream_t stream) {
  const float* H_op   = (const float*)d_in[0];
  const float* H_m    = (const float*)d_in[1];
  const int*   E_seq  = (const int*)d_in[2];
  const int*   E_op2m = (const int*)d_in[3];
  const float* W_op   = (const float*)d_in[4];
  const float* b_op   = (const float*)d_in[5];
  const float* W_m    = (const float*)d_in[6];
  const float* b_m    = (const float*)d_in[7];
  float* out = (float*)d_out;

  // ---- workspace layout (element offsets, 4B units unless noted) ----
  float* HmProj  = (float*)d_ws;                                //    256,000
  // zeroed region: degSeq|curSeq|degM|curM|bktCnt|bktCur
  int*   degSeq  = (int*)(HmProj + (size_t)N_M * OUT_DIM);      //    100,000
  int*   curSeq  = degSeq + N_OP;                               //    100,000
  int*   degM    = curSeq + N_OP;                               //      2,048
  int*   curM    = degM + 2048;                                 //      2,048
  int*   bktCnt  = curM + 2048;                                 //      1,024
  int*   bktCur  = bktCnt + 1024;                               //      1,024
  // end zeroed region (206,144 ints)
  int*   baseM   = bktCur + 1024;                               //      2,048
  int*   bktBase = baseM + 2048;                                //      1,024 (needs 783)
  int*   S       = bktBase + 1024;                              //    100,352
  int*   bsums   = S + 100352;                                  //        512
  unsigned* bktArr = (unsigned*)(bsums + 512);                  //  2,000,000
  int*   mL      = (int*)(bktArr + E_OP2M_N);                   //  2,000,000
  int*   seqL    = mL + E_OP2M_N;                               //    100,000
  unsigned short* HopProjH = (unsigned short*)(seqL + E_SEQ_N); // 12,800,000 ushort
  unsigned short* HmProjH  = HopProjH + (size_t)N_OP * OUT_DIM; //    256,000 ushort

  // 1. projections (ops: bf16 only; machines: fp32 + bf16)
  proj_kernel<<<(N_OP + 63) / 64, 256, 0, stream>>>(H_op, W_op, b_op, nullptr, HopProjH, N_OP);
  proj_kernel<<<(N_M + 63) / 64, 256, 0, stream>>>(H_m, W_m, b_m, HmProj, HmProjH, N_M);

  // 2. zero deg/cursor region (one contiguous memset)
  hipMemsetAsync(degSeq, 0, (size_t)(2 * N_OP + 2048 + 2048 + 1024 + 1024) * sizeof(int), stream);

  // 3. histograms
  hist2_kernel<<<256, 512, 0, stream>>>(E_seq, E_op2m, degSeq, degM, bktCnt);

  // 4. scans: baseM + bktBase (small), S over degSeq
  scan2_kernel<<<2, 256, 0, stream>>>(degM, baseM, bktCnt, bktBase);
  const int nScanBlocks = (SCAN_SEQ + 1023) / 1024;   // 98
  scanA_kernel<<<nScanBlocks, 256, 0, stream>>>(degSeq, S, bsums, SCAN_SEQ);
  scanB_kernel<<<1, 256, 0, stream>>>(bsums, nScanBlocks);
  scanC_kernel<<<nScanBlocks, 256, 0, stream>>>(S, bsums, SCAN_SEQ);

  // 5. fused locality-aware fill
  fill_fused_kernel<<<FILL_BLOCKS, 512, 0, stream>>>(E_seq, E_op2m, bktBase, baseM, S,
                                                     bktCur, curM, curSeq,
                                                     bktArr, mL, seqL);

  // 6. outputs
  op_out_b_kernel<<<NBKT, 512, 0, stream>>>(bktArr, HopProjH, HmProjH, bktBase, S, seqL, out);
  m_out_kernel<<<N_M, 512, 0, stream>>>(HopProjH, HmProj, mL, baseM, degM,
                                        out + (size_t)N_OP * OUT_DIM);
}

// Round 13
// 257.708 us; speedup vs baseline: 3.1224x; 1.0118x over previous
//
#include <hip/hip_runtime.h>

// Problem constants (match reference)
constexpr int N_OP    = 100000;
constexpr int N_M     = 2000;
constexpr int IN_DIM  = 64;
constexpr int OUT_DIM = 128;
constexpr int E_SEQ_N  = 100000;
constexpr int E_OP2M_N = 2000000;

// op-range bucketing: bucket = op >> 7 (128 ops per bucket)
constexpr int OPB_SHIFT = 7;
constexpr int OPB       = 128;
constexpr int NBKT      = (N_OP + OPB - 1) / OPB;   // 782
constexpr int FILL_BLOCKS = 256;
constexpr int FILL_CHUNK  = (E_OP2M_N + FILL_BLOCKS - 1) / FILL_BLOCKS;  // 7813
constexpr int SMCAP      = 4096;   // per-bucket LDS edge capacity (mean 2560, +30 sigma)

// fused output grid: groups of 7 blocks = 2 op-buckets + 5 machines
constexpr int OUT_GROUPS = 400;    // covers 782 op buckets (2/grp) and 2000 machines (5/grp)
constexpr int OUT_BLOCKS = OUT_GROUPS * 7;   // 2800

// seq scan: degSeq(100000) + trailing zero
constexpr int SCAN_SEQ = N_OP + 1;

__device__ __forceinline__ float bf2f(unsigned short h) {
  return __uint_as_float((unsigned)h << 16);
}
__device__ __forceinline__ unsigned short f2bf(float x) {
  unsigned u = __float_as_uint(x);
  u += 0x7fffu + ((u >> 16) & 1u);      // RNE
  return (unsigned short)(u >> 16);
}

// ---------------- Projection: Y[nrows,128] = X[nrows,64] @ W[64,128] + b ----------------
__global__ __launch_bounds__(256) void proj_kernel(
    const float* __restrict__ X, const float* __restrict__ W,
    const float* __restrict__ b, float* __restrict__ Y,
    unsigned short* __restrict__ Yh, int nrows) {
  __shared__ float4 Ws4[IN_DIM * 32];   // 32 KB
  __shared__ float4 Xs4[64 * 16];       // 16 KB
  __shared__ float4 Bs4[32];
  const int t = threadIdx.x;
  const float4* W4 = reinterpret_cast<const float4*>(W);
  #pragma unroll
  for (int k = 0; k < 8; ++k) Ws4[t + k * 256] = W4[t + k * 256];
  if (t < 32) Bs4[t] = reinterpret_cast<const float4*>(b)[t];
  const int row0 = blockIdx.x * 64;
  const float4* X4 = reinterpret_cast<const float4*>(X);
  const int maxQ = nrows * 16;
  #pragma unroll
  for (int k = 0; k < 4; ++k) {
    const int i = t + k * 256;
    const int gi = row0 * 16 + i;
    Xs4[i] = (gi < maxQ) ? X4[gi] : make_float4(0.f, 0.f, 0.f, 0.f);
  }
  __syncthreads();

  const int q = t & 31;     // column quad
  const int s = t >> 5;     // row slot
  const float4 bias = Bs4[q];
  float4 acc[8];
  #pragma unroll
  for (int rr = 0; rr < 8; ++rr) acc[rr] = bias;

  for (int j4 = 0; j4 < 16; ++j4) {
    float4 xv[8];
    #pragma unroll
    for (int rr = 0; rr < 8; ++rr) xv[rr] = Xs4[(s * 8 + rr) * 16 + j4];
    #pragma unroll
    for (int jj = 0; jj < 4; ++jj) {
      const float4 w4 = Ws4[(j4 * 4 + jj) * 32 + q];
      #pragma unroll
      for (int rr = 0; rr < 8; ++rr) {
        const float xj = (jj == 0) ? xv[rr].x : (jj == 1) ? xv[rr].y
                       : (jj == 2) ? xv[rr].z : xv[rr].w;
        acc[rr].x = fmaf(xj, w4.x, acc[rr].x);
        acc[rr].y = fmaf(xj, w4.y, acc[rr].y);
        acc[rr].z = fmaf(xj, w4.z, acc[rr].z);
        acc[rr].w = fmaf(xj, w4.w, acc[rr].w);
      }
    }
  }

  #pragma unroll
  for (int rr = 0; rr < 8; ++rr) {
    const int row = row0 + s * 8 + rr;
    if (row >= nrows) break;
    if (Y) *reinterpret_cast<float4*>(Y + (size_t)row * OUT_DIM + q * 4) = acc[rr];
    ushort4 hh;
    hh.x = f2bf(acc[rr].x); hh.y = f2bf(acc[rr].y);
    hh.z = f2bf(acc[rr].z); hh.w = f2bf(acc[rr].w);
    *reinterpret_cast<ushort4*>(Yh + (size_t)row * OUT_DIM + q * 4) = hh;
  }
}

// ---------------- degrees: bucket + machine hists in LDS; seq via global atomics ----------------
__global__ __launch_bounds__(512) void hist2_kernel(
    const int* __restrict__ Eseq, const int* __restrict__ Eop2m,
    int* __restrict__ degSeq, int* __restrict__ degM, int* __restrict__ bktCnt) {
  __shared__ int hm[N_M];    // 8 KB
  __shared__ int hb[NBKT];   // 3.1 KB
  for (int i = threadIdx.x; i < N_M; i += 512) hm[i] = 0;
  for (int i = threadIdx.x; i < NBKT; i += 512) hb[i] = 0;
  __syncthreads();
  const int stride = gridDim.x * 512;
  const int i0 = blockIdx.x * 512 + threadIdx.x;
  for (int e = i0; e < E_OP2M_N; e += stride) {
    atomicAdd(&hb[Eop2m[e] >> OPB_SHIFT], 1);
    atomicAdd(&hm[Eop2m[E_OP2M_N + e]], 1);
  }
  for (int e = i0; e < E_SEQ_N; e += stride)
    atomicAdd(&degSeq[Eseq[E_SEQ_N + e]], 1);
  __syncthreads();
  for (int i = threadIdx.x; i < N_M; i += 512) if (hm[i]) atomicAdd(&degM[i], hm[i]);
  for (int i = threadIdx.x; i < NBKT; i += 512) if (hb[i]) atomicAdd(&bktCnt[i], hb[i]);
}

// ---------------- small scans: block 0 -> baseM (2000); block 1 -> bktBase (782 + total) ----------------
__global__ __launch_bounds__(256) void scan2_kernel(
    const int* __restrict__ degM, int* __restrict__ baseM,
    const int* __restrict__ bktCnt, int* __restrict__ bktBase) {
  __shared__ int s[256];
  const int t = threadIdx.x;
  if (blockIdx.x == 0) {
    int v[8];
    int sum = 0;
    #pragma unroll
    for (int k = 0; k < 8; ++k) {
      const int i = t * 8 + k;
      v[k] = (i < N_M) ? degM[i] : 0;
      sum += v[k];
    }
    s[t] = sum;
    __syncthreads();
    for (int d = 1; d < 256; d <<= 1) {
      const int x = s[t];
      const int y = (t >= d) ? s[t - d] : 0;
      __syncthreads();
      s[t] = x + y;
      __syncthreads();
    }
    int run = s[t] - sum;
    #pragma unroll
    for (int k = 0; k < 8; ++k) {
      const int i = t * 8 + k;
      if (i < N_M) baseM[i] = run;
      run += v[k];
    }
  } else {
    int v[4];
    int sum = 0;
    #pragma unroll
    for (int k = 0; k < 4; ++k) {
      const int i = t * 4 + k;
      v[k] = (i < NBKT) ? bktCnt[i] : 0;
      sum += v[k];
    }
    s[t] = sum;
    __syncthreads();
    for (int d = 1; d < 256; d <<= 1) {
      const int x = s[t];
      const int y = (t >= d) ? s[t - d] : 0;
      __syncthreads();
      s[t] = x + y;
      __syncthreads();
    }
    int run = s[t] - sum;
    #pragma unroll
    for (int k = 0; k < 4; ++k) {
      const int i = t * 4 + k;
      if (i <= NBKT) bktBase[i] = run;
      run += v[k];
    }
    if (t == 255) bktBase[NBKT] = s[255];
  }
}

// ---------------- Hierarchical exclusive scan over degSeq -> S ----------------
__global__ __launch_bounds__(256) void scanA_kernel(
    const int* __restrict__ in, int* __restrict__ out, int* __restrict__ blockSums, int n) {
  __shared__ int s[256];
  const int base = blockIdx.x * 1024 + threadIdx.x * 4;
  int v[4];
  #pragma unroll
  for (int k = 0; k < 4; ++k) v[k] = (base + k < n) ? in[base + k] : 0;
  const int tsum = v[0] + v[1] + v[2] + v[3];
  s[threadIdx.x] = tsum;
  __syncthreads();
  for (int d = 1; d < 256; d <<= 1) {
    const int x = s[threadIdx.x];
    const int y = (threadIdx.x >= d) ? s[threadIdx.x - d] : 0;
    __syncthreads();
    s[threadIdx.x] = x + y;
    __syncthreads();
  }
  int run = s[threadIdx.x] - tsum;
  if (threadIdx.x == 255) blockSums[blockIdx.x] = s[255];
  #pragma unroll
  for (int k = 0; k < 4; ++k) {
    if (base + k < n) out[base + k] = run;
    run += v[k];
  }
}

__global__ __launch_bounds__(256) void scanB_kernel(int* __restrict__ bs, int nb) {
  __shared__ int s[256];
  const int t = threadIdx.x;
  const int v = (t < nb) ? bs[t] : 0;
  s[t] = v;
  __syncthreads();
  for (int d = 1; d < 256; d <<= 1) {
    const int x = s[t];
    const int y = (t >= d) ? s[t - d] : 0;
    __syncthreads();
    s[t] = x + y;
    __syncthreads();
  }
  if (t < nb) bs[t] = s[t] - v;
}

__global__ __launch_bounds__(256) void scanC_kernel(
    int* __restrict__ out, const int* __restrict__ bs, int n) {
  const int base = blockIdx.x * 1024 + threadIdx.x * 4;
  const int add = bs[blockIdx.x];
  #pragma unroll
  for (int k = 0; k < 4; ++k)
    if (base + k < n) out[base + k] += add;
}

// ---------------- fused fill: bktArr (op-major packed) + mL (m-major) + seqL ----------------
__global__ __launch_bounds__(512) void fill_fused_kernel(
    const int* __restrict__ Eseq, const int* __restrict__ Eop2m,
    const int* __restrict__ bktBase, const int* __restrict__ baseM, const int* __restrict__ S,
    int* __restrict__ bktCur, int* __restrict__ curM, int* __restrict__ curSeq,
    unsigned* __restrict__ bktArr, int* __restrict__ mL, int* __restrict__ seqL) {
  __shared__ int hb[NBKT], ofsB[NBKT], lcurB[NBKT];   // 9.4 KB
  __shared__ int hm[N_M], ofsM[N_M], lcurM[N_M];      // 24 KB
  for (int i = threadIdx.x; i < NBKT; i += 512) { hb[i] = 0; lcurB[i] = 0; }
  for (int i = threadIdx.x; i < N_M; i += 512)  { hm[i] = 0; lcurM[i] = 0; }
  __syncthreads();
  const int e0 = blockIdx.x * FILL_CHUNK;
  const int e1 = min(E_OP2M_N, e0 + FILL_CHUNK);
  for (int e = e0 + threadIdx.x; e < e1; e += 512) {
    atomicAdd(&hb[Eop2m[e] >> OPB_SHIFT], 1);
    atomicAdd(&hm[Eop2m[E_OP2M_N + e]], 1);
  }
  __syncthreads();
  for (int t = threadIdx.x; t < NBKT; t += 512) ofsB[t] = atomicAdd(&bktCur[t], hb[t]);
  for (int t = threadIdx.x; t < N_M; t += 512)  ofsM[t] = atomicAdd(&curM[t], hm[t]);
  __syncthreads();
  for (int e = e0 + threadIdx.x; e < e1; e += 512) {
    const int op = Eop2m[e];
    const int m  = Eop2m[E_OP2M_N + e];
    const int bb = op >> OPB_SHIFT;
    bktArr[bktBase[bb] + ofsB[bb] + atomicAdd(&lcurB[bb], 1)] = ((unsigned)op << 11) | (unsigned)m;
    mL[baseM[m] + ofsM[m] + atomicAdd(&lcurM[m], 1)] = op;
  }
  const int stride = gridDim.x * 512;
  for (int e = blockIdx.x * 512 + threadIdx.x; e < E_SEQ_N; e += stride) {
    const int src = Eseq[e];
    const int dst = Eseq[E_SEQ_N + e];
    seqL[S[dst] + atomicAdd(&curSeq[dst], 1)] = src;
  }
}

// ---------------- fused outputs: op-bucket blocks + machine blocks interleaved ----------------
// group g = bid/7, slot = bid%7: slot<2 -> op bucket 2g+slot; else machine 5g+slot-2.
__global__ __launch_bounds__(512) void out_fused_kernel(
    const unsigned* __restrict__ bktArr, const unsigned short* __restrict__ HopProjH,
    const unsigned short* __restrict__ HmProjH, const float* __restrict__ HmProj,
    const int* __restrict__ bktBase, const int* __restrict__ S, const int* __restrict__ seqL,
    const int* __restrict__ mL, const int* __restrict__ baseM, const int* __restrict__ degM,
    float* __restrict__ out) {
  __shared__ int h[OPB], s[OPB], ofs[OPB], lcur[OPB];
  __shared__ unsigned short sortedM[SMCAP];   // 8 KB
  __shared__ float red[16][129];              // 8.25 KB
  const int tid = threadIdx.x;
  const int g = blockIdx.x / 7;
  const int slot = blockIdx.x % 7;

  if (slot >= 2) {
    // ---------- machine path ----------
    const int m = g * 5 + (slot - 2);
    if (m >= N_M) return;
    const int s0 = baseM[m];
    const int deg = degM[m];
    const int c4   = (tid & 31) << 2;
    const int sl   = tid >> 5;
    float ax = 0.f, ay = 0.f, az = 0.f, aw = 0.f;
    int e = sl;
    for (; e + 48 < deg; e += 64) {
      const int o0 = mL[s0 + e];
      const int o1 = mL[s0 + e + 16];
      const int o2 = mL[s0 + e + 32];
      const int o3 = mL[s0 + e + 48];
      const ushort4 h0 = *reinterpret_cast<const ushort4*>(HopProjH + (size_t)o0 * OUT_DIM + c4);
      const ushort4 h1 = *reinterpret_cast<const ushort4*>(HopProjH + (size_t)o1 * OUT_DIM + c4);
      const ushort4 h2 = *reinterpret_cast<const ushort4*>(HopProjH + (size_t)o2 * OUT_DIM + c4);
      const ushort4 h3 = *reinterpret_cast<const ushort4*>(HopProjH + (size_t)o3 * OUT_DIM + c4);
      ax += (bf2f(h0.x) + bf2f(h1.x)) + (bf2f(h2.x) + bf2f(h3.x));
      ay += (bf2f(h0.y) + bf2f(h1.y)) + (bf2f(h2.y) + bf2f(h3.y));
      az += (bf2f(h0.z) + bf2f(h1.z)) + (bf2f(h2.z) + bf2f(h3.z));
      aw += (bf2f(h0.w) + bf2f(h1.w)) + (bf2f(h2.w) + bf2f(h3.w));
    }
    for (; e < deg; e += 16) {
      const int o = mL[s0 + e];
      const ushort4 hq = *reinterpret_cast<const ushort4*>(HopProjH + (size_t)o * OUT_DIM + c4);
      ax += bf2f(hq.x); ay += bf2f(hq.y); az += bf2f(hq.z); aw += bf2f(hq.w);
    }
    red[sl][c4 + 0] = ax;
    red[sl][c4 + 1] = ay;
    red[sl][c4 + 2] = az;
    red[sl][c4 + 3] = aw;
    __syncthreads();
    if (tid < 128) {
      const int col = tid;
      float sx = 0.f;
      #pragma unroll
      for (int k = 0; k < 16; ++k) sx += red[k][col];
      const float v = HmProj[m * OUT_DIM + col] + sx / (float)max(deg, 1);
      out[(size_t)N_OP * OUT_DIM + m * OUT_DIM + col] = fmaxf(v, 0.f);
    }
    return;
  }

  // ---------- op-bucket path ----------
  const int b = g * 2 + slot;
  if (b >= NBKT) return;
  const int opLo = b << OPB_SHIFT;
  const int opHi = min(opLo + OPB, N_OP);
  const int nOps = opHi - opLo;
  const int e0 = bktBase[b];
  const int n = min(bktBase[b + 1] - e0, SMCAP);

  if (tid < OPB) { h[tid] = 0; lcur[tid] = 0; }
  __syncthreads();
  for (int i = tid; i < n; i += 512)
    atomicAdd(&h[(int)(bktArr[e0 + i] >> 11) - opLo], 1);
  __syncthreads();
  if (tid < OPB) s[tid] = h[tid];
  __syncthreads();
  for (int d = 1; d < OPB; d <<= 1) {
    int x = 0, y = 0;
    if (tid < OPB) { x = s[tid]; y = (tid >= d) ? s[tid - d] : 0; }
    __syncthreads();
    if (tid < OPB) s[tid] = x + y;
    __syncthreads();
  }
  if (tid < OPB) ofs[tid] = s[tid] - h[tid];
  __syncthreads();
  for (int i = tid; i < n; i += 512) {
    const unsigned pk = bktArr[e0 + i];
    const int r = (int)(pk >> 11) - opLo;
    const int p = ofs[r] + atomicAdd(&lcur[r], 1);
    sortedM[p] = (unsigned short)(pk & 2047u);
  }
  __syncthreads();

  const int wave = tid >> 6;    // 0..7
  const int lane = tid & 63;
  for (int qq = 0; qq < 16; ++qq) {
    const int r = wave * 16 + qq;
    if (r >= nOps) break;
    const int i = opLo + r;
    const ushort2 hs = *reinterpret_cast<const ushort2*>(HopProjH + (size_t)i * OUT_DIM + lane * 2);
    float2 acc = make_float2(bf2f(hs.x), bf2f(hs.y));

    const int s0 = S[i];
    const int s1 = S[i + 1];
    float2 a = make_float2(0.f, 0.f);
    for (int e = s0; e < s1; ++e) {
      const int src = seqL[e];
      const ushort2 hh = *reinterpret_cast<const ushort2*>(HopProjH + (size_t)src * OUT_DIM + lane * 2);
      a.x += bf2f(hh.x); a.y += bf2f(hh.y);
    }
    const float wS = 1.0f / (float)max(s1 - s0, 1);
    acc.x += a.x * wS; acc.y += a.y * wS;

    const int k0 = ofs[r];
    const int k1 = k0 + h[r];
    float2 bb = make_float2(0.f, 0.f);
    int k = k0;
    for (; k + 8 <= k1; k += 8) {
      ushort2 hv[8];
      #pragma unroll
      for (int u = 0; u < 8; ++u) {
        const int mu = sortedM[k + u];
        hv[u] = *reinterpret_cast<const ushort2*>(HmProjH + (size_t)mu * OUT_DIM + lane * 2);
      }
      #pragma unroll
      for (int u = 0; u < 8; ++u) {
        bb.x += bf2f(hv[u].x);
        bb.y += bf2f(hv[u].y);
      }
    }
    for (; k < k1; ++k) {
      const int m0 = sortedM[k];
      const ushort2 h0 = *reinterpret_cast<const ushort2*>(HmProjH + (size_t)m0 * OUT_DIM + lane * 2);
      bb.x += bf2f(h0.x); bb.y += bf2f(h0.y);
    }
    const float wO = 1.0f / (float)max(k1 - k0, 1);
    acc.x = fmaxf(acc.x + bb.x * wO, 0.f);
    acc.y = fmaxf(acc.y + bb.y * wO, 0.f);
    *reinterpret_cast<float2*>(out + (size_t)i * OUT_DIM + lane * 2) = acc;
  }
}

extern "C" void kernel_launch(void* const* d_in, const int* in_sizes, int n_in,
                              void* d_out, int out_size, void* d_ws, size_t ws_size,
                              hipStream_t stream) {
  const float* H_op   = (const float*)d_in[0];
  const float* H_m    = (const float*)d_in[1];
  const int*   E_seq  = (const int*)d_in[2];
  const int*   E_op2m = (const int*)d_in[3];
  const float* W_op   = (const float*)d_in[4];
  const float* b_op   = (const float*)d_in[5];
  const float* W_m    = (const float*)d_in[6];
  const float* b_m    = (const float*)d_in[7];
  float* out = (float*)d_out;

  // ---- workspace layout (element offsets, 4B units unless noted) ----
  float* HmProj  = (float*)d_ws;                                //    256,000
  // zeroed region: degSeq|curSeq|degM|curM|bktCnt|bktCur
  int*   degSeq  = (int*)(HmProj + (size_t)N_M * OUT_DIM);      //    100,000
  int*   curSeq  = degSeq + N_OP;                               //    100,000
  int*   degM    = curSeq + N_OP;                               //      2,048
  int*   curM    = degM + 2048;                                 //      2,048
  int*   bktCnt  = curM + 2048;                                 //      1,024
  int*   bktCur  = bktCnt + 1024;                               //      1,024
  // end zeroed region (206,144 ints)
  int*   baseM   = bktCur + 1024;                               //      2,048
  int*   bktBase = baseM + 2048;                                //      1,024 (needs 783)
  int*   S       = bktBase + 1024;                              //    100,352
  int*   bsums   = S + 100352;                                  //        512
  unsigned* bktArr = (unsigned*)(bsums + 512);                  //  2,000,000
  int*   mL      = (int*)(bktArr + E_OP2M_N);                   //  2,000,000
  int*   seqL    = mL + E_OP2M_N;                               //    100,000
  unsigned short* HopProjH = (unsigned short*)(seqL + E_SEQ_N); // 12,800,000 ushort
  unsigned short* HmProjH  = HopProjH + (size_t)N_OP * OUT_DIM; //    256,000 ushort

  // 1. projections (ops: bf16 only; machines: fp32 + bf16)
  proj_kernel<<<(N_OP + 63) / 64, 256, 0, stream>>>(H_op, W_op, b_op, nullptr, HopProjH, N_OP);
  proj_kernel<<<(N_M + 63) / 64, 256, 0, stream>>>(H_m, W_m, b_m, HmProj, HmProjH, N_M);

  // 2. zero deg/cursor region (one contiguous memset)
  hipMemsetAsync(degSeq, 0, (size_t)(2 * N_OP + 2048 + 2048 + 1024 + 1024) * sizeof(int), stream);

  // 3. histograms
  hist2_kernel<<<256, 512, 0, stream>>>(E_seq, E_op2m, degSeq, degM, bktCnt);

  // 4. scans: baseM + bktBase (small), S over degSeq
  scan2_kernel<<<2, 256, 0, stream>>>(degM, baseM, bktCnt, bktBase);
  const int nScanBlocks = (SCAN_SEQ + 1023) / 1024;   // 98
  scanA_kernel<<<nScanBlocks, 256, 0, stream>>>(degSeq, S, bsums, SCAN_SEQ);
  scanB_kernel<<<1, 256, 0, stream>>>(bsums, nScanBlocks);
  scanC_kernel<<<nScanBlocks, 256, 0, stream>>>(S, bsums, SCAN_SEQ);

  // 5. fused locality-aware fill
  fill_fused_kernel<<<FILL_BLOCKS, 512, 0, stream>>>(E_seq, E_op2m, bktBase, baseM, S,
                                                     bktCur, curM, curSeq,
                                                     bktArr, mL, seqL);

  // 6. fused outputs (op buckets + machines interleaved for pipe diversity)
  out_fused_kernel<<<OUT_BLOCKS, 512, 0, stream>>>(bktArr, HopProjH, HmProjH, HmProj,
                                                   bktBase, S, seqL, mL, baseM, degM, out);
}